// Round 8
// baseline (1338.195 us; speedup 1.0000x reference)
//
#include <hip/hip_runtime.h>

#define N_ENTS 50000
#define R2 500
#define H 256
#define TSTEPS 4
#define NE 200000
#define NM 200000
#define NL 2
#define SLOPE 0.22916666666666666f
#define SCAN_NB ((N_ENTS + 255) / 256)   // 196
#define CPAD 16                           // one cache line per counter
#define GB_MAIN 391                       // gemm_big main blocks (ceil(50000/128))
#define GB_FIX 64                         // fixup tail blocks

typedef __attribute__((ext_vector_type(8))) short short8;
typedef __attribute__((ext_vector_type(4))) short short4v;
typedef __attribute__((ext_vector_type(4))) float f32x4;

static __device__ __forceinline__ float b2f(short s) {
  unsigned u = ((unsigned)(unsigned short)s) << 16;
  return __builtin_bit_cast(float, u);
}
static __device__ __forceinline__ short f2b(float f) {
  unsigned u = __builtin_bit_cast(unsigned, f);
  u = (u + 0x7FFFu + ((u >> 16) & 1u)) >> 16;
  return (short)(unsigned short)u;
}

static __device__ __forceinline__ void gload16(const short* g, short* l) {
  __builtin_amdgcn_global_load_lds(
      (const __attribute__((address_space(1))) void*)g,
      (__attribute__((address_space(3))) void*)l, 16, 0, 0);
}

// ---------------- big GEMM + fused deg==0 fixup ----------------------------------
// Main blocks (0..GB_MAIN-1): C[M x 256] = A[M x 512](bf16) * Bt[256 x 512]^T,
//   128x256 tile, BK=64, global_load_lds + XOR slot-swizzle; rows with deg==0
//   are NOT written (fixup owns them).
// Tail blocks (GB_MAIN..): rrelu(hc @ evolve_w^T) for deg==0 rows (+l2norm EPI2).
// EPI 1: Obf = bf16(rrelu(acc));  EPI 2: l2norm(rrelu(acc)) -> Cf f32 (+Obf bf16)
template<int EPI>
__global__ __launch_bounds__(256, 2)
void gemm_big(const short* __restrict__ A, int lda,
              const short* __restrict__ Bt, int ldb,
              int M, int K,
              float* __restrict__ Cf, int ldc,
              short* __restrict__ Obf, int ldo,
              const unsigned* __restrict__ degv,
              const unsigned* __restrict__ nz, const unsigned* __restrict__ zl,
              const short* __restrict__ evt_l)
{
  __shared__ short As[128 * 64];
  __shared__ short Bs[256 * 64];
  __shared__ float xs[H];
  __shared__ float redf[4];
  const int tid = threadIdx.x;

  if (blockIdx.x >= GB_MAIN) {           // ---- fixup tail ----
    const unsigned n = *nz;
    const short* wrow = evt_l + (long)tid * 256;
    for (unsigned zi = blockIdx.x - GB_MAIN; zi < n; zi += GB_FIX) {
      const int row = zl[zi];
      __syncthreads();
      xs[tid] = b2f(A[(long)row * lda + 256 + tid]);   // hc half of Acat
      __syncthreads();
      float acc = 0.f;
#pragma unroll
      for (int k0 = 0; k0 < H; k0 += 8) {
        short8 wv = *(const short8*)&wrow[k0];
        acc += xs[k0]     * b2f(wv[0]) + xs[k0 + 1] * b2f(wv[1])
             + xs[k0 + 2] * b2f(wv[2]) + xs[k0 + 3] * b2f(wv[3])
             + xs[k0 + 4] * b2f(wv[4]) + xs[k0 + 5] * b2f(wv[5])
             + xs[k0 + 6] * b2f(wv[6]) + xs[k0 + 7] * b2f(wv[7]);
      }
      float v = acc >= 0.f ? acc : acc * SLOPE;
      if (EPI == 2) {
        float s = v * v;
        s += __shfl_xor(s, 1, 64);  s += __shfl_xor(s, 2, 64);
        s += __shfl_xor(s, 4, 64);  s += __shfl_xor(s, 8, 64);
        s += __shfl_xor(s, 16, 64); s += __shfl_xor(s, 32, 64);
        const int w = tid >> 6;
        if ((tid & 63) == 0) redf[w] = s;
        __syncthreads();
        float tot = (redf[0] + redf[1]) + (redf[2] + redf[3]);
        float sc = 1.f / fmaxf(sqrtf(tot), 1e-12f);
        v *= sc;
        Cf[(long)row * ldc + tid] = v;
      }
      if (Obf) Obf[(long)row * ldo + tid] = f2b(v);
    }
    return;
  }

  const int w = tid >> 6, lane = tid & 63;
  const int fr = lane & 15, fq = lane >> 4;
  const int rowh = w >> 1, colh = w & 1;
  const int blk0 = blockIdx.x * 128;
  const int l8 = lane >> 3, s7 = lane & 7;

  f32x4 acc[4][8];
#pragma unroll
  for (int m = 0; m < 4; ++m)
#pragma unroll
    for (int n = 0; n < 8; ++n) {
      acc[m][n][0] = 0.f; acc[m][n][1] = 0.f; acc[m][n][2] = 0.f; acc[m][n][3] = 0.f;
    }

  for (int kc = 0; kc < K; kc += 64) {
    __syncthreads();
#pragma unroll
    for (int i = 0; i < 4; ++i) {          // A tile: 128 rows x 64 k
      int row = w * 32 + i * 8 + l8;
      int grow = min(blk0 + row, M - 1);
      const short* g = A + (size_t)grow * lda + kc + ((s7 ^ (row & 7)) << 3);
      gload16(g, As + w * 2048 + i * 512);
    }
#pragma unroll
    for (int i = 0; i < 8; ++i) {          // B tile: 256 cols x 64 k
      int row = w * 64 + i * 8 + l8;
      const short* g = Bt + (size_t)row * ldb + kc + ((s7 ^ (row & 7)) << 3);
      gload16(g, Bs + w * 4096 + i * 512);
    }
    __syncthreads();
#pragma unroll
    for (int ks = 0; ks < 2; ++ks) {
      const int sl = ((((ks << 2) | fq) ^ s7) << 3);
      short8 a[4], b[8];
#pragma unroll
      for (int m = 0; m < 4; ++m)
        a[m] = *(const short8*)&As[(rowh * 64 + m * 16 + fr) * 64 + sl];
#pragma unroll
      for (int n = 0; n < 8; ++n)
        b[n] = *(const short8*)&Bs[(colh * 128 + n * 16 + fr) * 64 + sl];
#pragma unroll
      for (int m = 0; m < 4; ++m)
#pragma unroll
        for (int n = 0; n < 8; ++n)
          acc[m][n] = __builtin_amdgcn_mfma_f32_16x16x32_bf16(a[m], b[n], acc[m][n], 0, 0, 0);
    }
  }

  if (EPI == 1) {
#pragma unroll
    for (int m = 0; m < 4; ++m)
#pragma unroll
      for (int j = 0; j < 4; ++j) {
        const int r = blk0 + rowh * 64 + m * 16 + fq * 4 + j;
        if (r < M && degv[r] != 0u) {
#pragma unroll
          for (int n = 0; n < 8; ++n) {
            const int col = colh * 128 + n * 16 + fr;
            float v = acc[m][n][j];
            v = v >= 0.f ? v : v * SLOPE;
            Obf[(size_t)r * ldo + col] = f2b(v);
          }
        }
      }
  } else {
    float ss[4][4];
#pragma unroll
    for (int m = 0; m < 4; ++m)
#pragma unroll
      for (int j = 0; j < 4; ++j) ss[m][j] = 0.f;
#pragma unroll
    for (int m = 0; m < 4; ++m)
#pragma unroll
      for (int n = 0; n < 8; ++n)
#pragma unroll
        for (int j = 0; j < 4; ++j) {
          float v = acc[m][n][j];
          v = v >= 0.f ? v : v * SLOPE;
          acc[m][n][j] = v;
          ss[m][j] += v * v;
        }
#pragma unroll
    for (int m = 0; m < 4; ++m)
#pragma unroll
      for (int j = 0; j < 4; ++j) {
        float s = ss[m][j];
        s += __shfl_xor(s, 1, 64);
        s += __shfl_xor(s, 2, 64);
        s += __shfl_xor(s, 4, 64);
        s += __shfl_xor(s, 8, 64);
        ss[m][j] = s;                      // half-row (128-col) sum, all lanes
      }
    __syncthreads();                       // compute done; reuse Bs
    float* red = (float*)Bs;               // [0..255]: partials, [256..511]: inv
    if (colh == 0 && fr == 0) {
#pragma unroll
      for (int m = 0; m < 4; ++m)
#pragma unroll
        for (int j = 0; j < 4; ++j)
          red[rowh * 128 + m * 16 + fq * 4 + j] = ss[m][j];
    }
    __syncthreads();
    float inv[4][4];
    if (colh == 1) {
#pragma unroll
      for (int m = 0; m < 4; ++m)
#pragma unroll
        for (int j = 0; j < 4; ++j) {
          float tot = ss[m][j] + red[rowh * 128 + m * 16 + fq * 4 + j];
          inv[m][j] = 1.f / fmaxf(sqrtf(tot), 1e-12f);
        }
      if (fr == 0) {
#pragma unroll
        for (int m = 0; m < 4; ++m)
#pragma unroll
          for (int j = 0; j < 4; ++j)
            red[256 + rowh * 128 + m * 16 + fq * 4 + j] = inv[m][j];
      }
    }
    __syncthreads();
    if (colh == 0) {
#pragma unroll
      for (int m = 0; m < 4; ++m)
#pragma unroll
        for (int j = 0; j < 4; ++j)
          inv[m][j] = red[256 + rowh * 128 + m * 16 + fq * 4 + j];
    }
#pragma unroll
    for (int m = 0; m < 4; ++m)
#pragma unroll
      for (int j = 0; j < 4; ++j) {
        const int r = blk0 + rowh * 64 + m * 16 + fq * 4 + j;
        if (r < M && degv[r] != 0u) {
#pragma unroll
          for (int n = 0; n < 8; ++n) {
            const int col = colh * 128 + n * 16 + fr;
            float v = acc[m][n][j] * inv[m][j];
            Cf[(size_t)r * ldc + col] = v;
            if (Obf) Obf[(size_t)r * ldo + col] = f2b(v);
          }
        }
      }
  }
}

// ---------------- small GEMM (init only): C = A * Bt^T (+bias), f32 out ----------
__global__ __launch_bounds__(256)
void gemm_k(const short* __restrict__ A, int lda,
            const short* __restrict__ Bt, int ldb,
            int M, int K,
            float* __restrict__ Cf, int ldc,
            const float* __restrict__ bias)
{
  __shared__ short bt[256 * 72];
  const int tid = threadIdx.x;
  const int w = tid >> 6;
  const int lane = tid & 63;
  const int fr = lane & 15;
  const int fq = lane >> 4;
  const int col0 = blockIdx.y << 8;
  const int rowbase = blockIdx.x * 64 + w * 16;
  const int arow = min(rowbase + fr, M - 1);
  const long abase = (long)arow * lda + fq * 8;

  f32x4 acc[16];
#pragma unroll
  for (int i = 0; i < 16; ++i) { acc[i][0] = 0.f; acc[i][1] = 0.f; acc[i][2] = 0.f; acc[i][3] = 0.f; }

  for (int kc = 0; kc < K; kc += 64) {
    __syncthreads();
    {
      const short* g = Bt + (long)(col0 + tid) * ldb + kc;
      short* l = &bt[tid * 72];
#pragma unroll
      for (int i = 0; i < 8; ++i)
        *(short8*)(l + i * 8) = *(const short8*)(g + i * 8);
    }
    __syncthreads();
#pragma unroll
    for (int ks = 0; ks < 2; ++ks) {
      short8 a = *(const short8*)(A + abase + kc + ks * 32);
#pragma unroll
      for (int ct = 0; ct < 16; ++ct) {
        short8 b = *(const short8*)&bt[(ct * 16 + fr) * 72 + ks * 32 + fq * 8];
        acc[ct] = __builtin_amdgcn_mfma_f32_16x16x32_bf16(a, b, acc[ct], 0, 0, 0);
      }
    }
  }

  const int crow = rowbase + fq * 4;
#pragma unroll
  for (int ct = 0; ct < 16; ++ct) {
    const int gcol = col0 + ct * 16 + fr;
#pragma unroll
    for (int j = 0; j < 4; ++j) {
      const int r = crow + j;
      if (r < M) {
        float v = acc[ct][j];
        if (bias) v += bias[gcol];
        Cf[(long)r * ldc + gcol] = v;
      }
    }
  }
}

// ---------------- fused GRU GEMMs: z=0 -> gx (A built from xinf), z=1 -> gh -------
__global__ __launch_bounds__(256)
void gru2_k(const float* __restrict__ xinf, const unsigned* __restrict__ cnt,
            const short* __restrict__ h0b,
            const short* __restrict__ wihb, const short* __restrict__ whhb,
            const float* __restrict__ gxbase, const float* __restrict__ bhh,
            float* __restrict__ gx, float* __restrict__ gh)
{
  const int z = blockIdx.z;
  const short* Bt;  int ldb;
  float* Cf;  const float* Cadd;  const float* bias;
  if (z == 0) { Bt = wihb + 256; ldb = 512; Cf = gx; Cadd = gxbase; bias = nullptr; }
  else        { Bt = whhb;       ldb = 256; Cf = gh; Cadd = nullptr; bias = bhh; }

  __shared__ short bt[256 * 72];
  const int tid = threadIdx.x;
  const int w = tid >> 6;
  const int lane = tid & 63;
  const int fr = lane & 15;
  const int fq = lane >> 4;
  const int col0 = blockIdx.y << 8;
  const int rowbase = blockIdx.x * 64 + w * 16;
  const int arow = min(rowbase + fr, R2 - 1);
  const long abase = (long)arow * 256 + fq * 8;
  float invc = 1.f;
  if (z == 0) invc = 1.f / fmaxf((float)cnt[arow * CPAD], 1.f);

  f32x4 acc[16];
#pragma unroll
  for (int i = 0; i < 16; ++i) { acc[i][0] = 0.f; acc[i][1] = 0.f; acc[i][2] = 0.f; acc[i][3] = 0.f; }

  for (int kc = 0; kc < 256; kc += 64) {
    __syncthreads();
    {
      const short* g = Bt + (long)(col0 + tid) * ldb + kc;
      short* l = &bt[tid * 72];
#pragma unroll
      for (int i = 0; i < 8; ++i)
        *(short8*)(l + i * 8) = *(const short8*)(g + i * 8);
    }
    __syncthreads();
#pragma unroll
    for (int ks = 0; ks < 2; ++ks) {
      short8 a;
      if (z == 0) {
        const long kb = abase + kc + ks * 32;      // = arow*256 + k
        f32x4 s0 = *(const f32x4*)&xinf[kb];
        f32x4 s1 = *(const f32x4*)&xinf[(long)R2 * 256 + kb];
        f32x4 s2 = *(const f32x4*)&xinf[(long)2 * R2 * 256 + kb];
        f32x4 s3 = *(const f32x4*)&xinf[(long)3 * R2 * 256 + kb];
        f32x4 t0 = *(const f32x4*)&xinf[kb + 4];
        f32x4 t1 = *(const f32x4*)&xinf[(long)R2 * 256 + kb + 4];
        f32x4 t2 = *(const f32x4*)&xinf[(long)2 * R2 * 256 + kb + 4];
        f32x4 t3 = *(const f32x4*)&xinf[(long)3 * R2 * 256 + kb + 4];
#pragma unroll
        for (int j = 0; j < 4; ++j) {
          a[j]     = f2b(((s0[j] + s1[j]) + (s2[j] + s3[j])) * invc);
          a[4 + j] = f2b(((t0[j] + t1[j]) + (t2[j] + t3[j])) * invc);
        }
      } else {
        a = *(const short8*)(h0b + abase + kc + ks * 32);
      }
#pragma unroll
      for (int ct = 0; ct < 16; ++ct) {
        short8 b = *(const short8*)&bt[(ct * 16 + fr) * 72 + ks * 32 + fq * 8];
        acc[ct] = __builtin_amdgcn_mfma_f32_16x16x32_bf16(a, b, acc[ct], 0, 0, 0);
      }
    }
  }

  const int crow = rowbase + fq * 4;
#pragma unroll
  for (int ct = 0; ct < 16; ++ct) {
    const int gcol = col0 + ct * 16 + fr;
#pragma unroll
    for (int j = 0; j < 4; ++j) {
      const int r = crow + j;
      if (r < R2) {
        float v = acc[ct][j];
        if (Cadd) v += Cadd[(long)r * 768 + gcol];
        if (bias) v += bias[gcol];
        Cf[(long)r * 768 + gcol] = v;
      }
    }
  }
}

// ---------------- init: h = l2norm(dynamic_emb) -> bf16 into Acat halfB ----------
__global__ __launch_bounds__(256)
void l2init_k(const float* __restrict__ de, short* __restrict__ hb)
{
  const int w = threadIdx.x >> 6, lane = threadIdx.x & 63;
  const int row = blockIdx.x * 4 + w;
  f32x4 v = *(const f32x4*)&de[(long)row * H + lane * 4];
  float s = v[0]*v[0] + v[1]*v[1] + v[2]*v[2] + v[3]*v[3];
  s += __shfl_xor(s, 1, 64);  s += __shfl_xor(s, 2, 64);
  s += __shfl_xor(s, 4, 64);  s += __shfl_xor(s, 8, 64);
  s += __shfl_xor(s, 16, 64); s += __shfl_xor(s, 32, 64);
  float sc = 1.f / fmaxf(sqrtf(s), 1e-12f);
  short4v o;
  o[0] = f2b(v[0]*sc); o[1] = f2b(v[1]*sc); o[2] = f2b(v[2]*sc); o[3] = f2b(v[3]*sc);
  *(short4v*)&hb[(long)row * 512 + lane * 4] = o;
}

// ---------------- merged weight prep ---------------------------------------------
__global__ __launch_bounds__(256)
void prep_k(const float* __restrict__ wn, const float* __restrict__ lw,
            const float* __restrict__ ew, const float* __restrict__ wih,
            const float* __restrict__ whh, const float* __restrict__ erel,
            short* __restrict__ wcatb, short* __restrict__ evt,
            short* __restrict__ wihb, short* __restrict__ whhb,
            short* __restrict__ erelb, float* __restrict__ h0, short* __restrict__ h0b)
{
  long i = (long)blockIdx.x * 256 + threadIdx.x;
  if (i < (long)NL * 256 * 512) {
    int l = (int)(i / (256 * 512));
    int rem = (int)(i % (256 * 512));
    int j = rem / 512;
    int k = rem % 512;
    float v = (k < 256) ? wn[(long)l * 65536 + k * 256 + j]
                        : lw[(long)l * 65536 + (k - 256) * 256 + j];
    wcatb[i] = f2b(v);
    return;
  }
  i -= (long)NL * 256 * 512;
  if (i < (long)NL * 65536) {
    int l = (int)(i >> 16);
    int rem = (int)(i & 65535);
    int c = rem >> 8, k = rem & 255;
    evt[i] = f2b(ew[(long)l * 65536 + k * 256 + c]);
    return;
  }
  i -= (long)NL * 65536;
  if (i < 768 * 512) { wihb[i] = f2b(wih[i]); return; }
  i -= 768 * 512;
  if (i < 768 * 256) { whhb[i] = f2b(whh[i]); return; }
  i -= 768 * 256;
  if (i < (long)R2 * H) {
    float v = erel[i];
    erelb[i] = f2b(v); h0[i] = v; h0b[i] = f2b(v);
  }
}
#define PREP_N ((long)NL * 256 * 512 + (long)NL * 65536 + 768 * 512 + 768 * 256 + (long)R2 * H)

// ---------------- batched zero of all 4 steps' counters (padded) ------------------
__global__ __launch_bounds__(256)
void zero_all_k(unsigned* __restrict__ deg, unsigned* __restrict__ curd,
                unsigned* __restrict__ cnt, unsigned* __restrict__ cur,
                unsigned* __restrict__ nz, unsigned* __restrict__ flags)
{
  const int t = blockIdx.y;
  int i = blockIdx.x * 256 + threadIdx.x;
  if (i < N_ENTS) { deg[(long)t * N_ENTS + i] = 0u; curd[(long)t * N_ENTS + i] = 0u; }
  if (i < R2) { cnt[((long)t * R2 + i) * CPAD] = 0u; cur[((long)t * R2 + i) * CPAD] = 0u; }
  if (i < SCAN_NB) flags[t * SCAN_NB + i] = 0u;
  if (i == 0) nz[t * CPAD] = 0u;
}

// ---------------- batched counting: rel histogram (LDS) + dst degree --------------
__global__ __launch_bounds__(256)
void count_all_k(const int* __restrict__ relA, const int* __restrict__ dstA,
                 unsigned* __restrict__ cntA, unsigned* __restrict__ degA)
{
  const int t = blockIdx.y;
  const int* rel = relA + (long)t * NM;
  const int* dstv = dstA + (long)t * NE;
  unsigned* cnt = cntA + (long)t * R2 * CPAD;
  unsigned* deg = degA + (long)t * N_ENTS;
  __shared__ unsigned lh[R2];
  for (int i = threadIdx.x; i < R2; i += 256) lh[i] = 0;
  __syncthreads();
  for (long i = (long)blockIdx.x * 256 + threadIdx.x; i < NM; i += (long)gridDim.x * 256)
    atomicAdd(&lh[rel[i]], 1u);
  for (long i = (long)blockIdx.x * 256 + threadIdx.x; i < NE; i += (long)gridDim.x * 256)
    atomicAdd(&deg[dstv[i]], 1u);
  __syncthreads();
  for (int i = threadIdx.x; i < R2; i += 256)
    if (lh[i]) atomicAdd(&cnt[i * CPAD], lh[i]);
}

// ---------------- batched scans: decoupled lookback (deg) + rel prefix ------------
__global__ __launch_bounds__(256)
void scan_all_k(const unsigned* __restrict__ degA, unsigned* __restrict__ offdA,
                unsigned* __restrict__ flagsA,
                unsigned* __restrict__ zlA, unsigned* __restrict__ nzA,
                const unsigned* __restrict__ cntA, unsigned* __restrict__ offA)
{
  const int t = blockIdx.y;
  if (blockIdx.x == SCAN_NB) {           // rel-histogram prefix (512-slot HS)
    const unsigned* cnt = cntA + (long)t * R2 * CPAD;
    unsigned* off = offA + t * (R2 + 1);
    __shared__ unsigned sr[512];
    const int tt = threadIdx.x;
    sr[tt] = (tt < R2) ? cnt[tt * CPAD] : 0u;
    sr[tt + 256] = (tt + 256 < R2) ? cnt[(tt + 256) * CPAD] : 0u;
    __syncthreads();
#pragma unroll
    for (int d = 1; d < 512; d <<= 1) {
      unsigned v0 = (tt >= d) ? sr[tt - d] : 0u;
      unsigned v1 = (tt + 256 >= d) ? sr[tt + 256 - d] : 0u;
      __syncthreads();
      sr[tt] += v0; sr[tt + 256] += v1;
      __syncthreads();
    }
    if (tt < R2) off[tt] = (tt == 0) ? 0u : sr[tt - 1];
    if (tt + 256 < R2) off[tt + 256] = sr[tt + 255];
    if (tt == 0) off[R2] = sr[R2 - 1];
    return;
  }
  const unsigned* deg = degA + (long)t * N_ENTS;
  unsigned* offd = offdA + (long)t * (N_ENTS + 1);
  unsigned* flags = flagsA + t * SCAN_NB;
  unsigned* zl = zlA + (long)t * N_ENTS;
  unsigned* nz = nzA + t * CPAD;
  __shared__ unsigned s[256];
  __shared__ unsigned sexc;
  const int tid = threadIdx.x;
  const int b = blockIdx.x;
  const int i = b * 256 + tid;
  unsigned v = (i < N_ENTS) ? deg[i] : 0u;
  s[tid] = v;
  __syncthreads();
#pragma unroll
  for (int d = 1; d < 256; d <<= 1) {
    unsigned t2 = (tid >= d) ? s[tid - d] : 0u;
    __syncthreads();
    s[tid] += t2;
    __syncthreads();
  }
  const unsigned total = s[255];
  if (tid == 0) {
    if (b == 0) {
      __threadfence();
      atomicExch(&flags[0], (2u << 30) | total);
      sexc = 0u;
    } else {
      __threadfence();
      atomicExch(&flags[b], (1u << 30) | total);
      unsigned exc = 0u;
      int j = b - 1;
      while (j >= 0) {
        unsigned f;
        do { f = atomicAdd(&flags[j], 0u); } while ((f >> 30) == 0u);
        exc += f & 0x3FFFFFFFu;
        if ((f >> 30) == 2u) break;
        --j;
      }
      __threadfence();
      atomicExch(&flags[b], (2u << 30) | (exc + total));
      sexc = exc;
    }
  }
  __syncthreads();
  const unsigned exc = sexc;
  if (i < N_ENTS) {
    offd[i] = exc + s[tid] - v;
    if (v == 0u) { unsigned p2 = atomicAdd(nz, 1u); zl[p2] = i; }
  }
  if (i == 0) offd[N_ENTS] = NE;
}

// ---------------- batched scatter: rel-CSR (ent) + dst-CSR (src,etype int2) ------
__global__ __launch_bounds__(256)
void scatter_all_k(const int* __restrict__ relA, const int* __restrict__ entA,
                   const unsigned* __restrict__ offA, unsigned* __restrict__ curA,
                   int* __restrict__ seA,
                   const int* __restrict__ srcA, const int* __restrict__ dstA,
                   const int* __restrict__ etA, const unsigned* __restrict__ offdA,
                   unsigned* __restrict__ curdA, int2* __restrict__ se2A)
{
  const int t = blockIdx.y;
  if (blockIdx.x < 256) {
    const int* rel = relA + (long)t * NM;
    const int* ent = entA + (long)t * NM;
    const unsigned* off = offA + t * (R2 + 1);
    unsigned* cur = curA + (long)t * R2 * CPAD;
    int* se = seA + (long)t * NM;
    for (long i = (long)blockIdx.x * 256 + threadIdx.x; i < NM; i += 256l * 256) {
      int r = rel[i];
      unsigned p = atomicAdd(&cur[r * CPAD], 1u);
      se[off[r] + p] = ent[i];
    }
  } else {
    const int* srcv = srcA + (long)t * NE;
    const int* dstv = dstA + (long)t * NE;
    const int* etv = etA + (long)t * NE;
    const unsigned* offd = offdA + (long)t * (N_ENTS + 1);
    unsigned* curd = curdA + (long)t * N_ENTS;
    int2* se2 = se2A + (long)t * NE;
    for (long i = (long)(blockIdx.x - 256) * 256 + threadIdx.x; i < NE; i += 512l * 256) {
      int d = dstv[i];
      unsigned p = atomicAdd(&curd[d], 1u);
      se2[offd[d] + p] = make_int2(srcv[i], etv[i]);
    }
  }
}

// ---------------- segment-sum partials (x4 split), 16B/lane, 2 entries/wave -------
__global__ __launch_bounds__(256)
void segpart_k(const unsigned* __restrict__ off, const int* __restrict__ se,
               const short* __restrict__ hb, float* __restrict__ xinf)
{
  __shared__ float red[4][256];
  const int r = blockIdx.x >> 2, s = blockIdx.x & 3;
  const int w = threadIdx.x >> 6, lane = threadIdx.x & 63;
  const int half = lane >> 5, sl = lane & 31;
  const unsigned b = off[r], e = off[r + 1], len = e - b;
  const unsigned lo = b + ((len * s) >> 2), hi = b + ((len * (s + 1)) >> 2);
  float a[8];
#pragma unroll
  for (int j = 0; j < 8; ++j) a[j] = 0.f;
  unsigned i = lo + w * 2;
  for (; i + 10 <= hi; i += 16) {          // two pairs per wave per iter
    int e0 = se[i + half];
    int e1 = se[i + 8 + half];
    short8 h0v = *(const short8*)&hb[(long)e0 * 512 + sl * 8];
    short8 h1v = *(const short8*)&hb[(long)e1 * 512 + sl * 8];
#pragma unroll
    for (int j = 0; j < 8; ++j) a[j] += b2f(h0v[j]) + b2f(h1v[j]);
  }
  for (; i + 2 <= hi; i += 8) {
    int e0 = se[i + half];
    short8 hv = *(const short8*)&hb[(long)e0 * 512 + sl * 8];
#pragma unroll
    for (int j = 0; j < 8; ++j) a[j] += b2f(hv[j]);
  }
  if (i + half < hi) {
    int e0 = se[i + half];
    short8 hv = *(const short8*)&hb[(long)e0 * 512 + sl * 8];
#pragma unroll
    for (int j = 0; j < 8; ++j) a[j] += b2f(hv[j]);
  }
#pragma unroll
  for (int j = 0; j < 8; ++j) a[j] += __shfl_xor(a[j], 32, 64);
  if (half == 0) {
#pragma unroll
    for (int j = 0; j < 8; ++j) red[w][sl * 8 + j] = a[j];
  }
  __syncthreads();
  const int t = threadIdx.x;
  xinf[((long)s * R2 + r) * 256 + t] =
      (red[0][t] + red[1][t]) + (red[2][t] + red[3][t]);
}

// ---------------- GRU gates ------------------------------------------------------
__global__ __launch_bounds__(256)
void gate_k(const float* __restrict__ gx, const float* __restrict__ gh,
            float* __restrict__ h0, short* __restrict__ h0b, float* __restrict__ relout)
{
  __shared__ float red[4];
  const int r = blockIdx.x, c = threadIdx.x;
  const long b = (long)r * 768;
  float xr = gx[b + c], xz = gx[b + 256 + c], xn = gx[b + 512 + c];
  float hr = gh[b + c], hz = gh[b + 256 + c], hn = gh[b + 512 + c];
  float rr = 1.f / (1.f + expf(-(xr + hr)));
  float z  = 1.f / (1.f + expf(-(xz + hz)));
  float nn = tanhf(xn + rr * hn);
  float v = (1.f - z) * nn + z * h0[(long)r * H + c];
  float s = v * v;
  s += __shfl_xor(s, 1, 64);  s += __shfl_xor(s, 2, 64);
  s += __shfl_xor(s, 4, 64);  s += __shfl_xor(s, 8, 64);
  s += __shfl_xor(s, 16, 64); s += __shfl_xor(s, 32, 64);
  const int w = c >> 6;
  if ((c & 63) == 0) red[w] = s;
  __syncthreads();
  float tot = (red[0] + red[1]) + (red[2] + red[3]);
  float sc = 1.f / fmaxf(sqrtf(tot), 1e-12f);
  v *= sc;
  h0[(long)r * H + c] = v;
  h0b[(long)r * H + c] = f2b(v);
  relout[(long)r * H + c] = v;
}

// ---------------- layer-0 aggregation: 16B/lane, 2 edges/wave, emits rsum --------
__global__ __launch_bounds__(256)
void agg_first_k(const int2* __restrict__ se2, const unsigned* __restrict__ offd,
                 const short* __restrict__ hb, const short* __restrict__ h0b,
                 short* __restrict__ rsum, short* __restrict__ acat)
{
  const int w = threadIdx.x >> 6, lane = threadIdx.x & 63;
  const int half = lane >> 5, sl = lane & 31;
  const int row = blockIdx.x * 4 + w;
  const unsigned b = offd[row], e = offd[row + 1];
  float ha[8], ra[8];
#pragma unroll
  for (int j = 0; j < 8; ++j) { ha[j] = 0.f; ra[j] = 0.f; }
  unsigned i = b;
  for (; i + 4 <= e; i += 4) {
    int2 e0 = se2[i + half];
    int2 e1 = se2[i + 2 + half];
    short8 h0v = *(const short8*)&hb[(long)e0.x * 512 + sl * 8];
    short8 r0v = *(const short8*)&h0b[(long)e0.y * 256 + sl * 8];
    short8 h1v = *(const short8*)&hb[(long)e1.x * 512 + sl * 8];
    short8 r1v = *(const short8*)&h0b[(long)e1.y * 256 + sl * 8];
#pragma unroll
    for (int j = 0; j < 8; ++j) {
      ha[j] += b2f(h0v[j]) + b2f(h1v[j]);
      ra[j] += b2f(r0v[j]) + b2f(r1v[j]);
    }
  }
  for (; i < e; i += 2) {
    if (i + half < e) {
      int2 e0 = se2[i + half];
      short8 hv = *(const short8*)&hb[(long)e0.x * 512 + sl * 8];
      short8 rv = *(const short8*)&h0b[(long)e0.y * 256 + sl * 8];
#pragma unroll
      for (int j = 0; j < 8; ++j) { ha[j] += b2f(hv[j]); ra[j] += b2f(rv[j]); }
    }
  }
#pragma unroll
  for (int j = 0; j < 8; ++j) {
    ha[j] += __shfl_xor(ha[j], 32, 64);
    ra[j] += __shfl_xor(ra[j], 32, 64);
  }
  if (half == 0) {
    const float nm = 1.f / fmaxf((float)(e - b), 1.f);
    short8 rs, o;
#pragma unroll
    for (int j = 0; j < 8; ++j) {
      rs[j] = f2b(ra[j]);
      o[j] = f2b((ha[j] + ra[j]) * nm);
    }
    *(short8*)&rsum[(long)row * 256 + sl * 8] = rs;
    *(short8*)&acat[(long)row * 512 + sl * 8] = o;
  }
}

// ---------------- layer-1 aggregation: reuses rsum, 16B/lane, 2 edges/wave -------
__global__ __launch_bounds__(256)
void agg_second_k(const int2* __restrict__ se2, const unsigned* __restrict__ offd,
                  const short* __restrict__ hb, const short* __restrict__ rsum,
                  short* __restrict__ acat)
{
  const int w = threadIdx.x >> 6, lane = threadIdx.x & 63;
  const int half = lane >> 5, sl = lane & 31;
  const int row = blockIdx.x * 4 + w;
  const unsigned b = offd[row], e = offd[row + 1];
  float ha[8];
#pragma unroll
  for (int j = 0; j < 8; ++j) ha[j] = 0.f;
  unsigned i = b;
  for (; i + 4 <= e; i += 4) {
    int2 e0 = se2[i + half];
    int2 e1 = se2[i + 2 + half];
    short8 h0v = *(const short8*)&hb[(long)e0.x * 512 + sl * 8];
    short8 h1v = *(const short8*)&hb[(long)e1.x * 512 + sl * 8];
#pragma unroll
    for (int j = 0; j < 8; ++j) ha[j] += b2f(h0v[j]) + b2f(h1v[j]);
  }
  for (; i < e; i += 2) {
    if (i + half < e) {
      int2 e0 = se2[i + half];
      short8 hv = *(const short8*)&hb[(long)e0.x * 512 + sl * 8];
#pragma unroll
      for (int j = 0; j < 8; ++j) ha[j] += b2f(hv[j]);
    }
  }
#pragma unroll
  for (int j = 0; j < 8; ++j) ha[j] += __shfl_xor(ha[j], 32, 64);
  if (half == 0) {
    short8 rs = *(const short8*)&rsum[(long)row * 256 + sl * 8];
    const float nm = 1.f / fmaxf((float)(e - b), 1.f);
    short8 o;
#pragma unroll
    for (int j = 0; j < 8; ++j) o[j] = f2b((ha[j] + b2f(rs[j])) * nm);
    *(short8*)&acat[(long)row * 512 + sl * 8] = o;
  }
}

// =================================================================================
extern "C" void kernel_launch(void* const* d_in, const int* in_sizes, int n_in,
                              void* d_out, int out_size, void* d_ws, size_t ws_size,
                              hipStream_t stream)
{
  (void)in_sizes; (void)n_in; (void)out_size; (void)ws_size;
  const int* src = (const int*)d_in[0];
  const int* dst = (const int*)d_in[1];
  const int* ety = (const int*)d_in[2];
  const int* r2e_ent = (const int*)d_in[3];
  const int* r2e_rel = (const int*)d_in[4];
  const float* dyn = (const float*)d_in[5];
  const float* erel = (const float*)d_in[6];
  const float* wn = (const float*)d_in[7];
  const float* lw = (const float*)d_in[8];
  const float* ew = (const float*)d_in[9];
  const float* wih = (const float*)d_in[10];
  const float* whh = (const float*)d_in[11];
  const float* bih = (const float*)d_in[12];
  const float* bhh = (const float*)d_in[13];

  float* out = (float*)d_out;
  float* hist = out;
  float* rels = out + (long)TSTEPS * N_ENTS * H;

  char* p = (char*)d_ws;
  auto alloc = [&](size_t n) { char* r = p; p += (n + 255) & ~(size_t)255; return r; };
  short*    AcatA  = (short*)alloc((size_t)N_ENTS * 512 * 2);
  short*    AcatB  = (short*)alloc((size_t)N_ENTS * 512 * 2);
  short*    rsum   = (short*)alloc((size_t)N_ENTS * 256 * 2);
  unsigned* deg    = (unsigned*)alloc((size_t)TSTEPS * N_ENTS * 4);
  unsigned* offd   = (unsigned*)alloc((size_t)TSTEPS * (N_ENTS + 1) * 4);
  unsigned* curd   = (unsigned*)alloc((size_t)TSTEPS * N_ENTS * 4);
  unsigned* flags  = (unsigned*)alloc((size_t)TSTEPS * SCAN_NB * 4);
  int2*     se2    = (int2*)alloc((size_t)TSTEPS * NE * 8);
  unsigned* zl     = (unsigned*)alloc((size_t)TSTEPS * N_ENTS * 4);
  unsigned* nz     = (unsigned*)alloc((size_t)TSTEPS * CPAD * 4);
  unsigned* cnt    = (unsigned*)alloc((size_t)TSTEPS * R2 * CPAD * 4);
  unsigned* off    = (unsigned*)alloc((size_t)TSTEPS * (R2 + 1) * 4);
  unsigned* cur    = (unsigned*)alloc((size_t)TSTEPS * R2 * CPAD * 4);
  int*      se     = (int*)alloc((size_t)TSTEPS * NM * 4);
  float*    xinf   = (float*)alloc((size_t)4 * R2 * 256 * 4);
  float*    gxbase = (float*)alloc((size_t)R2 * 768 * 4);
  float*    gx     = (float*)alloc((size_t)R2 * 768 * 4);
  float*    gh     = (float*)alloc((size_t)R2 * 768 * 4);
  float*    h0     = (float*)alloc((size_t)R2 * H * 4);
  short*    h0b    = (short*)alloc((size_t)R2 * H * 2);
  short*    erelb  = (short*)alloc((size_t)R2 * H * 2);
  short*    wcatb  = (short*)alloc((size_t)NL * 256 * 512 * 2);
  short*    evt    = (short*)alloc((size_t)NL * H * H * 2);
  short*    wihb   = (short*)alloc((size_t)768 * 512 * 2);
  short*    whhb   = (short*)alloc((size_t)768 * 256 * 2);

  prep_k<<<(int)((PREP_N + 255) / 256), 256, 0, stream>>>(
      wn, lw, ew, wih, whh, erel, wcatb, evt, wihb, whhb, erelb, h0, h0b);
  l2init_k<<<N_ENTS / 4, 256, 0, stream>>>(dyn, AcatA + 256);

  // gx_base = emb_rel @ W_ih[:, :256]^T + b_ih   (step-invariant)
  gemm_k<<<dim3(8, 3), 256, 0, stream>>>(erelb, 256, wihb, 512, R2, 256,
                                         gxbase, 768, bih);

  // ---- batched CSR build for ALL steps (depends only on int inputs) -------------
  zero_all_k<<<dim3(SCAN_NB, TSTEPS), 256, 0, stream>>>(deg, curd, cnt, cur, nz, flags);
  count_all_k<<<dim3(512, TSTEPS), 256, 0, stream>>>(r2e_rel, dst, cnt, deg);
  scan_all_k<<<dim3(SCAN_NB + 1, TSTEPS), 256, 0, stream>>>(deg, offd, flags, zl, nz, cnt, off);
  scatter_all_k<<<dim3(768, TSTEPS), 256, 0, stream>>>(r2e_rel, r2e_ent, off, cur, se,
                                                       src, dst, ety, offd, curd, se2);

  short* Acur = AcatA;
  short* Anxt = AcatB;

  for (int t = 0; t < TSTEPS; ++t) {
    float* hist_t = hist + (long)t * N_ENTS * H;
    float* rels_t = rels + (long)t * R2 * H;
    const unsigned* off_t  = off + t * (R2 + 1);
    const int*      se_t   = se + (long)t * NM;
    const unsigned* offd_t = offd + (long)t * (N_ENTS + 1);
    const int2*     se2_t  = se2 + (long)t * NE;
    const unsigned* cnt_t  = cnt + (long)t * R2 * CPAD;
    const unsigned* nz_t   = nz + t * CPAD;
    const unsigned* zl_t   = zl + (long)t * N_ENTS;
    const unsigned* deg_t  = deg + (long)t * N_ENTS;

    // relation mean (split x4) + GRU (segfin fused into gru2 z=0 A-path)
    segpart_k<<<R2 * 4, 256, 0, stream>>>(off_t, se_t, Acur + 256, xinf);
    gru2_k<<<dim3(8, 3, 2), 256, 0, stream>>>(xinf, cnt_t, h0b, wihb, whhb,
                                              gxbase, bhh, gx, gh);
    gate_k<<<R2, 256, 0, stream>>>(gx, gh, h0, h0b, rels_t);

    // layer 0 (fixup fused as tail blocks; main epilogue skips deg==0 rows)
    agg_first_k<<<N_ENTS / 4, 256, 0, stream>>>(se2_t, offd_t, Acur + 256, h0b, rsum, Acur);
    gemm_big<1><<<GB_MAIN + GB_FIX, 256, 0, stream>>>(
        Acur, 512, wcatb, 512, N_ENTS, 512, nullptr, 0, Anxt + 256, 512,
        deg_t, nz_t, zl_t, evt);
    { short* tmp = Acur; Acur = Anxt; Anxt = tmp; }

    // layer 1
    agg_second_k<<<N_ENTS / 4, 256, 0, stream>>>(se2_t, offd_t, Acur + 256, rsum, Acur);
    const bool last = (t == TSTEPS - 1);
    gemm_big<2><<<GB_MAIN + GB_FIX, 256, 0, stream>>>(
        Acur, 512, wcatb + 256 * 512, 512, N_ENTS, 512, hist_t, 256,
        last ? nullptr : (Anxt + 256), 512,
        deg_t, nz_t, zl_t, evt + (long)H * H);
    { short* tmp = Acur; Acur = Anxt; Anxt = tmp; }
  }
}

// Round 9
// 1050.832 us; speedup vs baseline: 1.2735x; 1.2735x over previous
//
#include <hip/hip_runtime.h>

#define N_ENTS 50000
#define R2 500
#define H 256
#define TSTEPS 4
#define NE 200000
#define NM 200000
#define NL 2
#define SLOPE 0.22916666666666666f
#define SCAN_NB ((N_ENTS + 255) / 256)   // 196
#define CPAD 16                           // one cache line per counter

typedef __attribute__((ext_vector_type(8))) short short8;
typedef __attribute__((ext_vector_type(4))) short short4v;
typedef __attribute__((ext_vector_type(4))) float f32x4;

static __device__ __forceinline__ float b2f(short s) {
  unsigned u = ((unsigned)(unsigned short)s) << 16;
  return __builtin_bit_cast(float, u);
}
static __device__ __forceinline__ short f2b(float f) {
  unsigned u = __builtin_bit_cast(unsigned, f);
  u = (u + 0x7FFFu + ((u >> 16) & 1u)) >> 16;
  return (short)(unsigned short)u;
}

static __device__ __forceinline__ void gload16(const short* g, short* l) {
  __builtin_amdgcn_global_load_lds(
      (const __attribute__((address_space(1))) void*)g,
      (__attribute__((address_space(3))) void*)l, 16, 0, 0);
}

// ---------------- big GEMM: C[M x 256] = A[M x K](bf16) * Bt[256 x K](bf16)^T ----
// 128x256 block, BK=64, 4 waves x (64 rows x 128 cols), global_load_lds staging
// with XOR slot-swizzle (slot ^= row&7) on both source and read sides.
// EPI 1: Obf = bf16(rrelu(acc))                      (ldo)
// EPI 2: l2norm(rrelu(acc)) -> Cf (f32, ldc) and (if Obf) Obf (bf16, ldo)
template<int EPI>
__global__ __launch_bounds__(256, 2)
void gemm_big(const short* __restrict__ A, int lda,
              const short* __restrict__ Bt, int ldb,
              int M, int K,
              float* __restrict__ Cf, int ldc,
              short* __restrict__ Obf, int ldo)
{
  __shared__ short As[128 * 64];
  __shared__ short Bs[256 * 64];
  const int tid = threadIdx.x;
  const int w = tid >> 6, lane = tid & 63;
  const int fr = lane & 15, fq = lane >> 4;
  const int rowh = w >> 1, colh = w & 1;
  const int blk0 = blockIdx.x * 128;
  const int l8 = lane >> 3, s7 = lane & 7;

  f32x4 acc[4][8];
#pragma unroll
  for (int m = 0; m < 4; ++m)
#pragma unroll
    for (int n = 0; n < 8; ++n) {
      acc[m][n][0] = 0.f; acc[m][n][1] = 0.f; acc[m][n][2] = 0.f; acc[m][n][3] = 0.f;
    }

  for (int kc = 0; kc < K; kc += 64) {
    __syncthreads();
#pragma unroll
    for (int i = 0; i < 4; ++i) {          // A tile: 128 rows x 64 k
      int row = w * 32 + i * 8 + l8;
      int grow = min(blk0 + row, M - 1);
      const short* g = A + (size_t)grow * lda + kc + ((s7 ^ (row & 7)) << 3);
      gload16(g, As + w * 2048 + i * 512);
    }
#pragma unroll
    for (int i = 0; i < 8; ++i) {          // B tile: 256 cols x 64 k
      int row = w * 64 + i * 8 + l8;
      const short* g = Bt + (size_t)row * ldb + kc + ((s7 ^ (row & 7)) << 3);
      gload16(g, Bs + w * 4096 + i * 512);
    }
    __syncthreads();
#pragma unroll
    for (int ks = 0; ks < 2; ++ks) {
      const int sl = ((((ks << 2) | fq) ^ s7) << 3);
      short8 a[4], b[8];
#pragma unroll
      for (int m = 0; m < 4; ++m)
        a[m] = *(const short8*)&As[(rowh * 64 + m * 16 + fr) * 64 + sl];
#pragma unroll
      for (int n = 0; n < 8; ++n)
        b[n] = *(const short8*)&Bs[(colh * 128 + n * 16 + fr) * 64 + sl];
#pragma unroll
      for (int m = 0; m < 4; ++m)
#pragma unroll
        for (int n = 0; n < 8; ++n)
          acc[m][n] = __builtin_amdgcn_mfma_f32_16x16x32_bf16(a[m], b[n], acc[m][n], 0, 0, 0);
    }
  }

  if (EPI == 1) {
#pragma unroll
    for (int m = 0; m < 4; ++m)
#pragma unroll
      for (int n = 0; n < 8; ++n) {
        const int col = colh * 128 + n * 16 + fr;
#pragma unroll
        for (int j = 0; j < 4; ++j) {
          const int r = blk0 + rowh * 64 + m * 16 + fq * 4 + j;
          if (r < M) {
            float v = acc[m][n][j];
            v = v >= 0.f ? v : v * SLOPE;
            Obf[(size_t)r * ldo + col] = f2b(v);
          }
        }
      }
  } else {
    float ss[4][4];
#pragma unroll
    for (int m = 0; m < 4; ++m)
#pragma unroll
      for (int j = 0; j < 4; ++j) ss[m][j] = 0.f;
#pragma unroll
    for (int m = 0; m < 4; ++m)
#pragma unroll
      for (int n = 0; n < 8; ++n)
#pragma unroll
        for (int j = 0; j < 4; ++j) {
          float v = acc[m][n][j];
          v = v >= 0.f ? v : v * SLOPE;
          acc[m][n][j] = v;
          ss[m][j] += v * v;
        }
#pragma unroll
    for (int m = 0; m < 4; ++m)
#pragma unroll
      for (int j = 0; j < 4; ++j) {
        float s = ss[m][j];
        s += __shfl_xor(s, 1, 64);
        s += __shfl_xor(s, 2, 64);
        s += __shfl_xor(s, 4, 64);
        s += __shfl_xor(s, 8, 64);
        ss[m][j] = s;                      // half-row (128-col) sum, all lanes
      }
    __syncthreads();                       // compute done; reuse Bs
    float* red = (float*)Bs;               // [0..255]: partials, [256..511]: inv
    if (colh == 0 && fr == 0) {
#pragma unroll
      for (int m = 0; m < 4; ++m)
#pragma unroll
        for (int j = 0; j < 4; ++j)
          red[rowh * 128 + m * 16 + fq * 4 + j] = ss[m][j];
    }
    __syncthreads();
    float inv[4][4];
    if (colh == 1) {
#pragma unroll
      for (int m = 0; m < 4; ++m)
#pragma unroll
        for (int j = 0; j < 4; ++j) {
          float tot = ss[m][j] + red[rowh * 128 + m * 16 + fq * 4 + j];
          inv[m][j] = 1.f / fmaxf(sqrtf(tot), 1e-12f);
        }
      if (fr == 0) {
#pragma unroll
        for (int m = 0; m < 4; ++m)
#pragma unroll
          for (int j = 0; j < 4; ++j)
            red[256 + rowh * 128 + m * 16 + fq * 4 + j] = inv[m][j];
      }
    }
    __syncthreads();
    if (colh == 0) {
#pragma unroll
      for (int m = 0; m < 4; ++m)
#pragma unroll
        for (int j = 0; j < 4; ++j)
          inv[m][j] = red[256 + rowh * 128 + m * 16 + fq * 4 + j];
    }
#pragma unroll
    for (int m = 0; m < 4; ++m)
#pragma unroll
      for (int n = 0; n < 8; ++n) {
        const int col = colh * 128 + n * 16 + fr;
#pragma unroll
        for (int j = 0; j < 4; ++j) {
          const int r = blk0 + rowh * 64 + m * 16 + fq * 4 + j;
          if (r < M) {
            float v = acc[m][n][j] * inv[m][j];
            Cf[(size_t)r * ldc + col] = v;
            if (Obf) Obf[(size_t)r * ldo + col] = f2b(v);
          }
        }
      }
  }
}

// ---------------- small GEMM (init only): C = A * Bt^T (+bias), f32 out ----------
__global__ __launch_bounds__(256)
void gemm_k(const short* __restrict__ A, int lda,
            const short* __restrict__ Bt, int ldb,
            int M, int K,
            float* __restrict__ Cf, int ldc,
            const float* __restrict__ bias)
{
  __shared__ short bt[256 * 72];
  const int tid = threadIdx.x;
  const int w = tid >> 6;
  const int lane = tid & 63;
  const int fr = lane & 15;
  const int fq = lane >> 4;
  const int col0 = blockIdx.y << 8;
  const int rowbase = blockIdx.x * 64 + w * 16;
  const int arow = min(rowbase + fr, M - 1);
  const long abase = (long)arow * lda + fq * 8;

  f32x4 acc[16];
#pragma unroll
  for (int i = 0; i < 16; ++i) { acc[i][0] = 0.f; acc[i][1] = 0.f; acc[i][2] = 0.f; acc[i][3] = 0.f; }

  for (int kc = 0; kc < K; kc += 64) {
    __syncthreads();
    {
      const short* g = Bt + (long)(col0 + tid) * ldb + kc;
      short* l = &bt[tid * 72];
#pragma unroll
      for (int i = 0; i < 8; ++i)
        *(short8*)(l + i * 8) = *(const short8*)(g + i * 8);
    }
    __syncthreads();
#pragma unroll
    for (int ks = 0; ks < 2; ++ks) {
      short8 a = *(const short8*)(A + abase + kc + ks * 32);
#pragma unroll
      for (int ct = 0; ct < 16; ++ct) {
        short8 b = *(const short8*)&bt[(ct * 16 + fr) * 72 + ks * 32 + fq * 8];
        acc[ct] = __builtin_amdgcn_mfma_f32_16x16x32_bf16(a, b, acc[ct], 0, 0, 0);
      }
    }
  }

  const int crow = rowbase + fq * 4;
#pragma unroll
  for (int ct = 0; ct < 16; ++ct) {
    const int gcol = col0 + ct * 16 + fr;
#pragma unroll
    for (int j = 0; j < 4; ++j) {
      const int r = crow + j;
      if (r < M) {
        float v = acc[ct][j];
        if (bias) v += bias[gcol];
        Cf[(long)r * ldc + gcol] = v;
      }
    }
  }
}

// ---------------- fused GRU GEMMs: z=0 -> gx (A built from xinf), z=1 -> gh -------
__global__ __launch_bounds__(256)
void gru2_k(const float* __restrict__ xinf, const unsigned* __restrict__ cnt,
            const short* __restrict__ h0b,
            const short* __restrict__ wihb, const short* __restrict__ whhb,
            const float* __restrict__ gxbase, const float* __restrict__ bhh,
            float* __restrict__ gx, float* __restrict__ gh)
{
  const int z = blockIdx.z;
  const short* Bt;  int ldb;
  float* Cf;  const float* Cadd;  const float* bias;
  if (z == 0) { Bt = wihb + 256; ldb = 512; Cf = gx; Cadd = gxbase; bias = nullptr; }
  else        { Bt = whhb;       ldb = 256; Cf = gh; Cadd = nullptr; bias = bhh; }

  __shared__ short bt[256 * 72];
  const int tid = threadIdx.x;
  const int w = tid >> 6;
  const int lane = tid & 63;
  const int fr = lane & 15;
  const int fq = lane >> 4;
  const int col0 = blockIdx.y << 8;
  const int rowbase = blockIdx.x * 64 + w * 16;
  const int arow = min(rowbase + fr, R2 - 1);
  const long abase = (long)arow * 256 + fq * 8;
  float invc = 1.f;
  if (z == 0) invc = 1.f / fmaxf((float)cnt[arow * CPAD], 1.f);

  f32x4 acc[16];
#pragma unroll
  for (int i = 0; i < 16; ++i) { acc[i][0] = 0.f; acc[i][1] = 0.f; acc[i][2] = 0.f; acc[i][3] = 0.f; }

  for (int kc = 0; kc < 256; kc += 64) {
    __syncthreads();
    {
      const short* g = Bt + (long)(col0 + tid) * ldb + kc;
      short* l = &bt[tid * 72];
#pragma unroll
      for (int i = 0; i < 8; ++i)
        *(short8*)(l + i * 8) = *(const short8*)(g + i * 8);
    }
    __syncthreads();
#pragma unroll
    for (int ks = 0; ks < 2; ++ks) {
      short8 a;
      if (z == 0) {
        const long kb = abase + kc + ks * 32;      // = arow*256 + k
        f32x4 s0 = *(const f32x4*)&xinf[kb];
        f32x4 s1 = *(const f32x4*)&xinf[(long)R2 * 256 + kb];
        f32x4 s2 = *(const f32x4*)&xinf[(long)2 * R2 * 256 + kb];
        f32x4 s3 = *(const f32x4*)&xinf[(long)3 * R2 * 256 + kb];
        f32x4 t0 = *(const f32x4*)&xinf[kb + 4];
        f32x4 t1 = *(const f32x4*)&xinf[(long)R2 * 256 + kb + 4];
        f32x4 t2 = *(const f32x4*)&xinf[(long)2 * R2 * 256 + kb + 4];
        f32x4 t3 = *(const f32x4*)&xinf[(long)3 * R2 * 256 + kb + 4];
#pragma unroll
        for (int j = 0; j < 4; ++j) {
          a[j]     = f2b(((s0[j] + s1[j]) + (s2[j] + s3[j])) * invc);
          a[4 + j] = f2b(((t0[j] + t1[j]) + (t2[j] + t3[j])) * invc);
        }
      } else {
        a = *(const short8*)(h0b + abase + kc + ks * 32);
      }
#pragma unroll
      for (int ct = 0; ct < 16; ++ct) {
        short8 b = *(const short8*)&bt[(ct * 16 + fr) * 72 + ks * 32 + fq * 8];
        acc[ct] = __builtin_amdgcn_mfma_f32_16x16x32_bf16(a, b, acc[ct], 0, 0, 0);
      }
    }
  }

  const int crow = rowbase + fq * 4;
#pragma unroll
  for (int ct = 0; ct < 16; ++ct) {
    const int gcol = col0 + ct * 16 + fr;
#pragma unroll
    for (int j = 0; j < 4; ++j) {
      const int r = crow + j;
      if (r < R2) {
        float v = acc[ct][j];
        if (Cadd) v += Cadd[(long)r * 768 + gcol];
        if (bias) v += bias[gcol];
        Cf[(long)r * 768 + gcol] = v;
      }
    }
  }
}

// ---------------- init: h = l2norm(dynamic_emb) -> bf16 into Acat halfB ----------
__global__ __launch_bounds__(256)
void l2init_k(const float* __restrict__ de, short* __restrict__ hb)
{
  const int w = threadIdx.x >> 6, lane = threadIdx.x & 63;
  const int row = blockIdx.x * 4 + w;
  f32x4 v = *(const f32x4*)&de[(long)row * H + lane * 4];
  float s = v[0]*v[0] + v[1]*v[1] + v[2]*v[2] + v[3]*v[3];
  s += __shfl_xor(s, 1, 64);  s += __shfl_xor(s, 2, 64);
  s += __shfl_xor(s, 4, 64);  s += __shfl_xor(s, 8, 64);
  s += __shfl_xor(s, 16, 64); s += __shfl_xor(s, 32, 64);
  float sc = 1.f / fmaxf(sqrtf(s), 1e-12f);
  short4v o;
  o[0] = f2b(v[0]*sc); o[1] = f2b(v[1]*sc); o[2] = f2b(v[2]*sc); o[3] = f2b(v[3]*sc);
  *(short4v*)&hb[(long)row * 512 + lane * 4] = o;
}

// ---------------- merged weight prep ---------------------------------------------
__global__ __launch_bounds__(256)
void prep_k(const float* __restrict__ wn, const float* __restrict__ lw,
            const float* __restrict__ ew, const float* __restrict__ wih,
            const float* __restrict__ whh, const float* __restrict__ erel,
            short* __restrict__ wcatb, short* __restrict__ evt,
            short* __restrict__ wihb, short* __restrict__ whhb,
            short* __restrict__ erelb, float* __restrict__ h0, short* __restrict__ h0b)
{
  long i = (long)blockIdx.x * 256 + threadIdx.x;
  if (i < (long)NL * 256 * 512) {
    int l = (int)(i / (256 * 512));
    int rem = (int)(i % (256 * 512));
    int j = rem / 512;
    int k = rem % 512;
    float v = (k < 256) ? wn[(long)l * 65536 + k * 256 + j]
                        : lw[(long)l * 65536 + (k - 256) * 256 + j];
    wcatb[i] = f2b(v);
    return;
  }
  i -= (long)NL * 256 * 512;
  if (i < (long)NL * 65536) {
    int l = (int)(i >> 16);
    int rem = (int)(i & 65535);
    int c = rem >> 8, k = rem & 255;
    evt[i] = f2b(ew[(long)l * 65536 + k * 256 + c]);
    return;
  }
  i -= (long)NL * 65536;
  if (i < 768 * 512) { wihb[i] = f2b(wih[i]); return; }
  i -= 768 * 512;
  if (i < 768 * 256) { whhb[i] = f2b(whh[i]); return; }
  i -= 768 * 256;
  if (i < (long)R2 * H) {
    float v = erel[i];
    erelb[i] = f2b(v); h0[i] = v; h0b[i] = f2b(v);
  }
}
#define PREP_N ((long)NL * 256 * 512 + (long)NL * 65536 + 768 * 512 + 768 * 256 + (long)R2 * H)

// ---------------- batched zero of all 4 steps' counters (padded) ------------------
__global__ __launch_bounds__(256)
void zero_all_k(unsigned* __restrict__ deg, unsigned* __restrict__ curd,
                unsigned* __restrict__ cnt, unsigned* __restrict__ cur,
                unsigned* __restrict__ nz, unsigned* __restrict__ flags)
{
  const int t = blockIdx.y;
  int i = blockIdx.x * 256 + threadIdx.x;
  if (i < N_ENTS) { deg[(long)t * N_ENTS + i] = 0u; curd[(long)t * N_ENTS + i] = 0u; }
  if (i < R2) { cnt[((long)t * R2 + i) * CPAD] = 0u; cur[((long)t * R2 + i) * CPAD] = 0u; }
  if (i < SCAN_NB) flags[t * SCAN_NB + i] = 0u;
  if (i == 0) nz[t * CPAD] = 0u;
}

// ---------------- batched counting: rel histogram (LDS) + dst degree --------------
__global__ __launch_bounds__(256)
void count_all_k(const int* __restrict__ relA, const int* __restrict__ dstA,
                 unsigned* __restrict__ cntA, unsigned* __restrict__ degA)
{
  const int t = blockIdx.y;
  const int* rel = relA + (long)t * NM;
  const int* dstv = dstA + (long)t * NE;
  unsigned* cnt = cntA + (long)t * R2 * CPAD;
  unsigned* deg = degA + (long)t * N_ENTS;
  __shared__ unsigned lh[R2];
  for (int i = threadIdx.x; i < R2; i += 256) lh[i] = 0;
  __syncthreads();
  for (long i = (long)blockIdx.x * 256 + threadIdx.x; i < NM; i += (long)gridDim.x * 256)
    atomicAdd(&lh[rel[i]], 1u);
  for (long i = (long)blockIdx.x * 256 + threadIdx.x; i < NE; i += (long)gridDim.x * 256)
    atomicAdd(&deg[dstv[i]], 1u);
  __syncthreads();
  for (int i = threadIdx.x; i < R2; i += 256)
    if (lh[i]) atomicAdd(&cnt[i * CPAD], lh[i]);
}

// ---------------- batched scans: decoupled lookback (deg) + rel prefix ------------
__global__ __launch_bounds__(256)
void scan_all_k(const unsigned* __restrict__ degA, unsigned* __restrict__ offdA,
                unsigned* __restrict__ flagsA,
                unsigned* __restrict__ zlA, unsigned* __restrict__ nzA,
                const unsigned* __restrict__ cntA, unsigned* __restrict__ offA)
{
  const int t = blockIdx.y;
  if (blockIdx.x == SCAN_NB) {           // rel-histogram prefix (512-slot HS)
    const unsigned* cnt = cntA + (long)t * R2 * CPAD;
    unsigned* off = offA + t * (R2 + 1);
    __shared__ unsigned sr[512];
    const int tt = threadIdx.x;
    sr[tt] = (tt < R2) ? cnt[tt * CPAD] : 0u;
    sr[tt + 256] = (tt + 256 < R2) ? cnt[(tt + 256) * CPAD] : 0u;
    __syncthreads();
#pragma unroll
    for (int d = 1; d < 512; d <<= 1) {
      unsigned v0 = (tt >= d) ? sr[tt - d] : 0u;
      unsigned v1 = (tt + 256 >= d) ? sr[tt + 256 - d] : 0u;
      __syncthreads();
      sr[tt] += v0; sr[tt + 256] += v1;
      __syncthreads();
    }
    if (tt < R2) off[tt] = (tt == 0) ? 0u : sr[tt - 1];
    if (tt + 256 < R2) off[tt + 256] = sr[tt + 255];
    if (tt == 0) off[R2] = sr[R2 - 1];
    return;
  }
  const unsigned* deg = degA + (long)t * N_ENTS;
  unsigned* offd = offdA + (long)t * (N_ENTS + 1);
  unsigned* flags = flagsA + t * SCAN_NB;
  unsigned* zl = zlA + (long)t * N_ENTS;
  unsigned* nz = nzA + t * CPAD;
  __shared__ unsigned s[256];
  __shared__ unsigned sexc;
  const int tid = threadIdx.x;
  const int b = blockIdx.x;
  const int i = b * 256 + tid;
  unsigned v = (i < N_ENTS) ? deg[i] : 0u;
  s[tid] = v;
  __syncthreads();
#pragma unroll
  for (int d = 1; d < 256; d <<= 1) {
    unsigned t2 = (tid >= d) ? s[tid - d] : 0u;
    __syncthreads();
    s[tid] += t2;
    __syncthreads();
  }
  const unsigned total = s[255];
  if (tid == 0) {
    if (b == 0) {
      __threadfence();
      atomicExch(&flags[0], (2u << 30) | total);
      sexc = 0u;
    } else {
      __threadfence();
      atomicExch(&flags[b], (1u << 30) | total);
      unsigned exc = 0u;
      int j = b - 1;
      while (j >= 0) {
        unsigned f;
        do { f = atomicAdd(&flags[j], 0u); } while ((f >> 30) == 0u);
        exc += f & 0x3FFFFFFFu;
        if ((f >> 30) == 2u) break;
        --j;
      }
      __threadfence();
      atomicExch(&flags[b], (2u << 30) | (exc + total));
      sexc = exc;
    }
  }
  __syncthreads();
  const unsigned exc = sexc;
  if (i < N_ENTS) {
    offd[i] = exc + s[tid] - v;
    if (v == 0u) { unsigned p2 = atomicAdd(nz, 1u); zl[p2] = i; }
  }
  if (i == 0) offd[N_ENTS] = NE;
}

// ---------------- batched scatter: rel-CSR (ent) + dst-CSR (src,etype int2) ------
__global__ __launch_bounds__(256)
void scatter_all_k(const int* __restrict__ relA, const int* __restrict__ entA,
                   const unsigned* __restrict__ offA, unsigned* __restrict__ curA,
                   int* __restrict__ seA,
                   const int* __restrict__ srcA, const int* __restrict__ dstA,
                   const int* __restrict__ etA, const unsigned* __restrict__ offdA,
                   unsigned* __restrict__ curdA, int2* __restrict__ se2A)
{
  const int t = blockIdx.y;
  if (blockIdx.x < 256) {
    const int* rel = relA + (long)t * NM;
    const int* ent = entA + (long)t * NM;
    const unsigned* off = offA + t * (R2 + 1);
    unsigned* cur = curA + (long)t * R2 * CPAD;
    int* se = seA + (long)t * NM;
    for (long i = (long)blockIdx.x * 256 + threadIdx.x; i < NM; i += 256l * 256) {
      int r = rel[i];
      unsigned p = atomicAdd(&cur[r * CPAD], 1u);
      se[off[r] + p] = ent[i];
    }
  } else {
    const int* srcv = srcA + (long)t * NE;
    const int* dstv = dstA + (long)t * NE;
    const int* etv = etA + (long)t * NE;
    const unsigned* offd = offdA + (long)t * (N_ENTS + 1);
    unsigned* curd = curdA + (long)t * N_ENTS;
    int2* se2 = se2A + (long)t * NE;
    for (long i = (long)(blockIdx.x - 256) * 256 + threadIdx.x; i < NE; i += 512l * 256) {
      int d = dstv[i];
      unsigned p = atomicAdd(&curd[d], 1u);
      se2[offd[d] + p] = make_int2(srcv[i], etv[i]);
    }
  }
}

// ---------------- segment-sum partials (x4 split), 16B/lane, 2 entries/wave -------
__global__ __launch_bounds__(256)
void segpart_k(const unsigned* __restrict__ off, const int* __restrict__ se,
               const short* __restrict__ hb, float* __restrict__ xinf)
{
  __shared__ float red[4][256];
  const int r = blockIdx.x >> 2, s = blockIdx.x & 3;
  const int w = threadIdx.x >> 6, lane = threadIdx.x & 63;
  const int half = lane >> 5, sl = lane & 31;
  const unsigned b = off[r], e = off[r + 1], len = e - b;
  const unsigned lo = b + ((len * s) >> 2), hi = b + ((len * (s + 1)) >> 2);
  float a[8];
#pragma unroll
  for (int j = 0; j < 8; ++j) a[j] = 0.f;
  unsigned i = lo + w * 2;
  for (; i + 10 <= hi; i += 16) {          // two pairs per wave per iter
    int e0 = se[i + half];
    int e1 = se[i + 8 + half];
    short8 h0v = *(const short8*)&hb[(long)e0 * 512 + sl * 8];
    short8 h1v = *(const short8*)&hb[(long)e1 * 512 + sl * 8];
#pragma unroll
    for (int j = 0; j < 8; ++j) a[j] += b2f(h0v[j]) + b2f(h1v[j]);
  }
  for (; i + 2 <= hi; i += 8) {
    int e0 = se[i + half];
    short8 hv = *(const short8*)&hb[(long)e0 * 512 + sl * 8];
#pragma unroll
    for (int j = 0; j < 8; ++j) a[j] += b2f(hv[j]);
  }
  if (i + half < hi) {
    int e0 = se[i + half];
    short8 hv = *(const short8*)&hb[(long)e0 * 512 + sl * 8];
#pragma unroll
    for (int j = 0; j < 8; ++j) a[j] += b2f(hv[j]);
  }
#pragma unroll
  for (int j = 0; j < 8; ++j) a[j] += __shfl_xor(a[j], 32, 64);
  if (half == 0) {
#pragma unroll
    for (int j = 0; j < 8; ++j) red[w][sl * 8 + j] = a[j];
  }
  __syncthreads();
  const int t = threadIdx.x;
  xinf[((long)s * R2 + r) * 256 + t] =
      (red[0][t] + red[1][t]) + (red[2][t] + red[3][t]);
}

// ---------------- GRU gates ------------------------------------------------------
__global__ __launch_bounds__(256)
void gate_k(const float* __restrict__ gx, const float* __restrict__ gh,
            float* __restrict__ h0, short* __restrict__ h0b, float* __restrict__ relout)
{
  __shared__ float red[4];
  const int r = blockIdx.x, c = threadIdx.x;
  const long b = (long)r * 768;
  float xr = gx[b + c], xz = gx[b + 256 + c], xn = gx[b + 512 + c];
  float hr = gh[b + c], hz = gh[b + 256 + c], hn = gh[b + 512 + c];
  float rr = 1.f / (1.f + expf(-(xr + hr)));
  float z  = 1.f / (1.f + expf(-(xz + hz)));
  float nn = tanhf(xn + rr * hn);
  float v = (1.f - z) * nn + z * h0[(long)r * H + c];
  float s = v * v;
  s += __shfl_xor(s, 1, 64);  s += __shfl_xor(s, 2, 64);
  s += __shfl_xor(s, 4, 64);  s += __shfl_xor(s, 8, 64);
  s += __shfl_xor(s, 16, 64); s += __shfl_xor(s, 32, 64);
  const int w = c >> 6;
  if ((c & 63) == 0) red[w] = s;
  __syncthreads();
  float tot = (red[0] + red[1]) + (red[2] + red[3]);
  float sc = 1.f / fmaxf(sqrtf(tot), 1e-12f);
  v *= sc;
  h0[(long)r * H + c] = v;
  h0b[(long)r * H + c] = f2b(v);
  relout[(long)r * H + c] = v;
}

// ---------------- layer-0 aggregation: 16B/lane, 2 edges/wave, emits rsum --------
__global__ __launch_bounds__(256)
void agg_first_k(const int2* __restrict__ se2, const unsigned* __restrict__ offd,
                 const short* __restrict__ hb, const short* __restrict__ h0b,
                 short* __restrict__ rsum, short* __restrict__ acat)
{
  const int w = threadIdx.x >> 6, lane = threadIdx.x & 63;
  const int half = lane >> 5, sl = lane & 31;
  const int row = blockIdx.x * 4 + w;
  const unsigned b = offd[row], e = offd[row + 1];
  float ha[8], ra[8];
#pragma unroll
  for (int j = 0; j < 8; ++j) { ha[j] = 0.f; ra[j] = 0.f; }
  unsigned i = b;
  for (; i + 4 <= e; i += 4) {
    int2 e0 = se2[i + half];
    int2 e1 = se2[i + 2 + half];
    short8 h0v = *(const short8*)&hb[(long)e0.x * 512 + sl * 8];
    short8 r0v = *(const short8*)&h0b[(long)e0.y * 256 + sl * 8];
    short8 h1v = *(const short8*)&hb[(long)e1.x * 512 + sl * 8];
    short8 r1v = *(const short8*)&h0b[(long)e1.y * 256 + sl * 8];
#pragma unroll
    for (int j = 0; j < 8; ++j) {
      ha[j] += b2f(h0v[j]) + b2f(h1v[j]);
      ra[j] += b2f(r0v[j]) + b2f(r1v[j]);
    }
  }
  for (; i < e; i += 2) {
    if (i + half < e) {
      int2 e0 = se2[i + half];
      short8 hv = *(const short8*)&hb[(long)e0.x * 512 + sl * 8];
      short8 rv = *(const short8*)&h0b[(long)e0.y * 256 + sl * 8];
#pragma unroll
      for (int j = 0; j < 8; ++j) { ha[j] += b2f(hv[j]); ra[j] += b2f(rv[j]); }
    }
  }
#pragma unroll
  for (int j = 0; j < 8; ++j) {
    ha[j] += __shfl_xor(ha[j], 32, 64);
    ra[j] += __shfl_xor(ra[j], 32, 64);
  }
  if (half == 0) {
    const float nm = 1.f / fmaxf((float)(e - b), 1.f);
    short8 rs, o;
#pragma unroll
    for (int j = 0; j < 8; ++j) {
      rs[j] = f2b(ra[j]);
      o[j] = f2b((ha[j] + ra[j]) * nm);
    }
    *(short8*)&rsum[(long)row * 256 + sl * 8] = rs;
    *(short8*)&acat[(long)row * 512 + sl * 8] = o;
  }
}

// ---------------- layer-1 aggregation: reuses rsum, 16B/lane, 2 edges/wave -------
__global__ __launch_bounds__(256)
void agg_second_k(const int2* __restrict__ se2, const unsigned* __restrict__ offd,
                  const short* __restrict__ hb, const short* __restrict__ rsum,
                  short* __restrict__ acat)
{
  const int w = threadIdx.x >> 6, lane = threadIdx.x & 63;
  const int half = lane >> 5, sl = lane & 31;
  const int row = blockIdx.x * 4 + w;
  const unsigned b = offd[row], e = offd[row + 1];
  float ha[8];
#pragma unroll
  for (int j = 0; j < 8; ++j) ha[j] = 0.f;
  unsigned i = b;
  for (; i + 4 <= e; i += 4) {
    int2 e0 = se2[i + half];
    int2 e1 = se2[i + 2 + half];
    short8 h0v = *(const short8*)&hb[(long)e0.x * 512 + sl * 8];
    short8 h1v = *(const short8*)&hb[(long)e1.x * 512 + sl * 8];
#pragma unroll
    for (int j = 0; j < 8; ++j) ha[j] += b2f(h0v[j]) + b2f(h1v[j]);
  }
  for (; i < e; i += 2) {
    if (i + half < e) {
      int2 e0 = se2[i + half];
      short8 hv = *(const short8*)&hb[(long)e0.x * 512 + sl * 8];
#pragma unroll
      for (int j = 0; j < 8; ++j) ha[j] += b2f(hv[j]);
    }
  }
#pragma unroll
  for (int j = 0; j < 8; ++j) ha[j] += __shfl_xor(ha[j], 32, 64);
  if (half == 0) {
    short8 rs = *(const short8*)&rsum[(long)row * 256 + sl * 8];
    const float nm = 1.f / fmaxf((float)(e - b), 1.f);
    short8 o;
#pragma unroll
    for (int j = 0; j < 8; ++j) o[j] = f2b((ha[j] + b2f(rs[j])) * nm);
    *(short8*)&acat[(long)row * 512 + sl * 8] = o;
  }
}

// ---------------- deg==0 fixup: row = rrelu(hc @ evolve_w) (+l2norm if final) ----
template<int FINAL>
__global__ __launch_bounds__(256)
void fixup_k(const unsigned* __restrict__ nz, const unsigned* __restrict__ zl,
             const short* __restrict__ hbc, const short* __restrict__ evt,
             short* __restrict__ hbn, float* __restrict__ outF)
{
  __shared__ float x[H];
  __shared__ float red[4];
  const unsigned n = *nz;
  const short* wrow = evt + (long)threadIdx.x * 256;
  for (unsigned zi = blockIdx.x; zi < n; zi += gridDim.x) {
    const int row = zl[zi];
    __syncthreads();
    x[threadIdx.x] = b2f(hbc[(long)row * 512 + threadIdx.x]);
    __syncthreads();
    float acc = 0.f;
#pragma unroll
    for (int k0 = 0; k0 < H; k0 += 8) {
      short8 wv = *(const short8*)&wrow[k0];
      acc += x[k0]     * b2f(wv[0]) + x[k0 + 1] * b2f(wv[1])
           + x[k0 + 2] * b2f(wv[2]) + x[k0 + 3] * b2f(wv[3])
           + x[k0 + 4] * b2f(wv[4]) + x[k0 + 5] * b2f(wv[5])
           + x[k0 + 6] * b2f(wv[6]) + x[k0 + 7] * b2f(wv[7]);
    }
    float v = acc >= 0.f ? acc : acc * SLOPE;
    if (FINAL) {
      float s = v * v;
      s += __shfl_xor(s, 1, 64);  s += __shfl_xor(s, 2, 64);
      s += __shfl_xor(s, 4, 64);  s += __shfl_xor(s, 8, 64);
      s += __shfl_xor(s, 16, 64); s += __shfl_xor(s, 32, 64);
      const int w = threadIdx.x >> 6;
      if ((threadIdx.x & 63) == 0) red[w] = s;
      __syncthreads();
      float tot = (red[0] + red[1]) + (red[2] + red[3]);
      float sc = 1.f / fmaxf(sqrtf(tot), 1e-12f);
      v *= sc;
      outF[(long)row * H + threadIdx.x] = v;
    }
    if (hbn) hbn[(long)row * 512 + threadIdx.x] = f2b(v);
  }
}

// =================================================================================
extern "C" void kernel_launch(void* const* d_in, const int* in_sizes, int n_in,
                              void* d_out, int out_size, void* d_ws, size_t ws_size,
                              hipStream_t stream)
{
  (void)in_sizes; (void)n_in; (void)out_size; (void)ws_size;
  const int* src = (const int*)d_in[0];
  const int* dst = (const int*)d_in[1];
  const int* ety = (const int*)d_in[2];
  const int* r2e_ent = (const int*)d_in[3];
  const int* r2e_rel = (const int*)d_in[4];
  const float* dyn = (const float*)d_in[5];
  const float* erel = (const float*)d_in[6];
  const float* wn = (const float*)d_in[7];
  const float* lw = (const float*)d_in[8];
  const float* ew = (const float*)d_in[9];
  const float* wih = (const float*)d_in[10];
  const float* whh = (const float*)d_in[11];
  const float* bih = (const float*)d_in[12];
  const float* bhh = (const float*)d_in[13];

  float* out = (float*)d_out;
  float* hist = out;
  float* rels = out + (long)TSTEPS * N_ENTS * H;

  char* p = (char*)d_ws;
  auto alloc = [&](size_t n) { char* r = p; p += (n + 255) & ~(size_t)255; return r; };
  short*    AcatA  = (short*)alloc((size_t)N_ENTS * 512 * 2);
  short*    AcatB  = (short*)alloc((size_t)N_ENTS * 512 * 2);
  short*    rsum   = (short*)alloc((size_t)N_ENTS * 256 * 2);
  unsigned* deg    = (unsigned*)alloc((size_t)TSTEPS * N_ENTS * 4);
  unsigned* offd   = (unsigned*)alloc((size_t)TSTEPS * (N_ENTS + 1) * 4);
  unsigned* curd   = (unsigned*)alloc((size_t)TSTEPS * N_ENTS * 4);
  unsigned* flags  = (unsigned*)alloc((size_t)TSTEPS * SCAN_NB * 4);
  int2*     se2    = (int2*)alloc((size_t)TSTEPS * NE * 8);
  unsigned* zl     = (unsigned*)alloc((size_t)TSTEPS * N_ENTS * 4);
  unsigned* nz     = (unsigned*)alloc((size_t)TSTEPS * CPAD * 4);
  unsigned* cnt    = (unsigned*)alloc((size_t)TSTEPS * R2 * CPAD * 4);
  unsigned* off    = (unsigned*)alloc((size_t)TSTEPS * (R2 + 1) * 4);
  unsigned* cur    = (unsigned*)alloc((size_t)TSTEPS * R2 * CPAD * 4);
  int*      se     = (int*)alloc((size_t)TSTEPS * NM * 4);
  float*    xinf   = (float*)alloc((size_t)4 * R2 * 256 * 4);
  float*    gxbase = (float*)alloc((size_t)R2 * 768 * 4);
  float*    gx     = (float*)alloc((size_t)R2 * 768 * 4);
  float*    gh     = (float*)alloc((size_t)R2 * 768 * 4);
  float*    h0     = (float*)alloc((size_t)R2 * H * 4);
  short*    h0b    = (short*)alloc((size_t)R2 * H * 2);
  short*    erelb  = (short*)alloc((size_t)R2 * H * 2);
  short*    wcatb  = (short*)alloc((size_t)NL * 256 * 512 * 2);
  short*    evt    = (short*)alloc((size_t)NL * H * H * 2);
  short*    wihb   = (short*)alloc((size_t)768 * 512 * 2);
  short*    whhb   = (short*)alloc((size_t)768 * 256 * 2);

  prep_k<<<(int)((PREP_N + 255) / 256), 256, 0, stream>>>(
      wn, lw, ew, wih, whh, erel, wcatb, evt, wihb, whhb, erelb, h0, h0b);
  l2init_k<<<N_ENTS / 4, 256, 0, stream>>>(dyn, AcatA + 256);

  // gx_base = emb_rel @ W_ih[:, :256]^T + b_ih   (step-invariant)
  gemm_k<<<dim3(8, 3), 256, 0, stream>>>(erelb, 256, wihb, 512, R2, 256,
                                         gxbase, 768, bih);

  // ---- batched CSR build for ALL steps (depends only on int inputs) -------------
  zero_all_k<<<dim3(SCAN_NB, TSTEPS), 256, 0, stream>>>(deg, curd, cnt, cur, nz, flags);
  count_all_k<<<dim3(512, TSTEPS), 256, 0, stream>>>(r2e_rel, dst, cnt, deg);
  scan_all_k<<<dim3(SCAN_NB + 1, TSTEPS), 256, 0, stream>>>(deg, offd, flags, zl, nz, cnt, off);
  scatter_all_k<<<dim3(768, TSTEPS), 256, 0, stream>>>(r2e_rel, r2e_ent, off, cur, se,
                                                       src, dst, ety, offd, curd, se2);

  short* Acur = AcatA;
  short* Anxt = AcatB;

  for (int t = 0; t < TSTEPS; ++t) {
    float* hist_t = hist + (long)t * N_ENTS * H;
    float* rels_t = rels + (long)t * R2 * H;
    const unsigned* off_t  = off + t * (R2 + 1);
    const int*      se_t   = se + (long)t * NM;
    const unsigned* offd_t = offd + (long)t * (N_ENTS + 1);
    const int2*     se2_t  = se2 + (long)t * NE;
    const unsigned* cnt_t  = cnt + (long)t * R2 * CPAD;
    const unsigned* nz_t   = nz + t * CPAD;
    const unsigned* zl_t   = zl + (long)t * N_ENTS;

    // relation mean (split x4) + GRU (segfin fused into gru2 z=0 A-path)
    segpart_k<<<R2 * 4, 256, 0, stream>>>(off_t, se_t, Acur + 256, xinf);
    gru2_k<<<dim3(8, 3, 2), 256, 0, stream>>>(xinf, cnt_t, h0b, wihb, whhb,
                                              gxbase, bhh, gx, gh);
    gate_k<<<R2, 256, 0, stream>>>(gx, gh, h0, h0b, rels_t);

    // layer 0
    agg_first_k<<<N_ENTS / 4, 256, 0, stream>>>(se2_t, offd_t, Acur + 256, h0b, rsum, Acur);
    gemm_big<1><<<391, 256, 0, stream>>>(Acur, 512, wcatb, 512,
                                         N_ENTS, 512, nullptr, 0, Anxt + 256, 512);
    fixup_k<0><<<512, 256, 0, stream>>>(nz_t, zl_t, Acur + 256, evt, Anxt + 256, nullptr);
    { short* tmp = Acur; Acur = Anxt; Anxt = tmp; }

    // layer 1
    agg_second_k<<<N_ENTS / 4, 256, 0, stream>>>(se2_t, offd_t, Acur + 256, rsum, Acur);
    const bool last = (t == TSTEPS - 1);
    gemm_big<2><<<391, 256, 0, stream>>>(Acur, 512, wcatb + 256 * 512, 512,
                                         N_ENTS, 512, hist_t, 256,
                                         last ? nullptr : (Anxt + 256), 512);
    fixup_k<1><<<512, 256, 0, stream>>>(nz_t, zl_t, Acur + 256, evt + (long)H * H,
                                        last ? nullptr : (Anxt + 256), hist_t);
    { short* tmp = Acur; Acur = Anxt; Anxt = tmp; }
  }
}

// Round 10
// 1018.976 us; speedup vs baseline: 1.3133x; 1.0313x over previous
//
#include <hip/hip_runtime.h>

#define N_ENTS 50000
#define R2 500
#define H 256
#define TSTEPS 4
#define NE 200000
#define NM 200000
#define NL 2
#define SLOPE 0.22916666666666666f
#define SCAN_NB ((N_ENTS + 255) / 256)   // 196
#define CPAD 16                           // one cache line per counter

typedef __attribute__((ext_vector_type(8))) short short8;
typedef __attribute__((ext_vector_type(4))) short short4v;
typedef __attribute__((ext_vector_type(4))) float f32x4;

static __device__ __forceinline__ float b2f(short s) {
  unsigned u = ((unsigned)(unsigned short)s) << 16;
  return __builtin_bit_cast(float, u);
}
static __device__ __forceinline__ short f2b(float f) {
  unsigned u = __builtin_bit_cast(unsigned, f);
  u = (u + 0x7FFFu + ((u >> 16) & 1u)) >> 16;
  return (short)(unsigned short)u;
}

static __device__ __forceinline__ void gload16(const short* g, short* l) {
  __builtin_amdgcn_global_load_lds(
      (const __attribute__((address_space(1))) void*)g,
      (__attribute__((address_space(3))) void*)l, 16, 0, 0);
}

// ---------------- big GEMM: C[M x 256] = A[M x K](bf16) * Bt[256 x K](bf16)^T ----
// 128x256 block, BK=64, 4 waves x (64 rows x 128 cols), global_load_lds staging
// with XOR slot-swizzle (slot ^= row&7) on both source and read sides.
// EPI 1: Obf = bf16(rrelu(acc))                      (ldo)
// EPI 2: l2norm(rrelu(acc)) -> Cf (f32, ldc) and (if Obf) Obf (bf16, ldo)
template<int EPI>
__global__ __launch_bounds__(256, 2)
void gemm_big(const short* __restrict__ A, int lda,
              const short* __restrict__ Bt, int ldb,
              int M, int K,
              float* __restrict__ Cf, int ldc,
              short* __restrict__ Obf, int ldo)
{
  __shared__ short As[128 * 64];
  __shared__ short Bs[256 * 64];
  const int tid = threadIdx.x;
  const int w = tid >> 6, lane = tid & 63;
  const int fr = lane & 15, fq = lane >> 4;
  const int rowh = w >> 1, colh = w & 1;
  const int blk0 = blockIdx.x * 128;
  const int l8 = lane >> 3, s7 = lane & 7;

  f32x4 acc[4][8];
#pragma unroll
  for (int m = 0; m < 4; ++m)
#pragma unroll
    for (int n = 0; n < 8; ++n) {
      acc[m][n][0] = 0.f; acc[m][n][1] = 0.f; acc[m][n][2] = 0.f; acc[m][n][3] = 0.f;
    }

  for (int kc = 0; kc < K; kc += 64) {
    __syncthreads();
#pragma unroll
    for (int i = 0; i < 4; ++i) {          // A tile: 128 rows x 64 k
      int row = w * 32 + i * 8 + l8;
      int grow = min(blk0 + row, M - 1);
      const short* g = A + (size_t)grow * lda + kc + ((s7 ^ (row & 7)) << 3);
      gload16(g, As + w * 2048 + i * 512);
    }
#pragma unroll
    for (int i = 0; i < 8; ++i) {          // B tile: 256 cols x 64 k
      int row = w * 64 + i * 8 + l8;
      const short* g = Bt + (size_t)row * ldb + kc + ((s7 ^ (row & 7)) << 3);
      gload16(g, Bs + w * 4096 + i * 512);
    }
    __syncthreads();
#pragma unroll
    for (int ks = 0; ks < 2; ++ks) {
      const int sl = ((((ks << 2) | fq) ^ s7) << 3);
      short8 a[4], b[8];
#pragma unroll
      for (int m = 0; m < 4; ++m)
        a[m] = *(const short8*)&As[(rowh * 64 + m * 16 + fr) * 64 + sl];
#pragma unroll
      for (int n = 0; n < 8; ++n)
        b[n] = *(const short8*)&Bs[(colh * 128 + n * 16 + fr) * 64 + sl];
#pragma unroll
      for (int m = 0; m < 4; ++m)
#pragma unroll
        for (int n = 0; n < 8; ++n)
          acc[m][n] = __builtin_amdgcn_mfma_f32_16x16x32_bf16(a[m], b[n], acc[m][n], 0, 0, 0);
    }
  }

  if (EPI == 1) {
#pragma unroll
    for (int m = 0; m < 4; ++m)
#pragma unroll
      for (int n = 0; n < 8; ++n) {
        const int col = colh * 128 + n * 16 + fr;
#pragma unroll
        for (int j = 0; j < 4; ++j) {
          const int r = blk0 + rowh * 64 + m * 16 + fq * 4 + j;
          if (r < M) {
            float v = acc[m][n][j];
            v = v >= 0.f ? v : v * SLOPE;
            Obf[(size_t)r * ldo + col] = f2b(v);
          }
        }
      }
  } else {
    float ss[4][4];
#pragma unroll
    for (int m = 0; m < 4; ++m)
#pragma unroll
      for (int j = 0; j < 4; ++j) ss[m][j] = 0.f;
#pragma unroll
    for (int m = 0; m < 4; ++m)
#pragma unroll
      for (int n = 0; n < 8; ++n)
#pragma unroll
        for (int j = 0; j < 4; ++j) {
          float v = acc[m][n][j];
          v = v >= 0.f ? v : v * SLOPE;
          acc[m][n][j] = v;
          ss[m][j] += v * v;
        }
#pragma unroll
    for (int m = 0; m < 4; ++m)
#pragma unroll
      for (int j = 0; j < 4; ++j) {
        float s = ss[m][j];
        s += __shfl_xor(s, 1, 64);
        s += __shfl_xor(s, 2, 64);
        s += __shfl_xor(s, 4, 64);
        s += __shfl_xor(s, 8, 64);
        ss[m][j] = s;                      // half-row (128-col) sum, all lanes
      }
    __syncthreads();                       // compute done; reuse Bs
    float* red = (float*)Bs;               // [0..255]: partials, [256..511]: inv
    if (colh == 0 && fr == 0) {
#pragma unroll
      for (int m = 0; m < 4; ++m)
#pragma unroll
        for (int j = 0; j < 4; ++j)
          red[rowh * 128 + m * 16 + fq * 4 + j] = ss[m][j];
    }
    __syncthreads();
    float inv[4][4];
    if (colh == 1) {
#pragma unroll
      for (int m = 0; m < 4; ++m)
#pragma unroll
        for (int j = 0; j < 4; ++j) {
          float tot = ss[m][j] + red[rowh * 128 + m * 16 + fq * 4 + j];
          inv[m][j] = 1.f / fmaxf(sqrtf(tot), 1e-12f);
        }
      if (fr == 0) {
#pragma unroll
        for (int m = 0; m < 4; ++m)
#pragma unroll
          for (int j = 0; j < 4; ++j)
            red[256 + rowh * 128 + m * 16 + fq * 4 + j] = inv[m][j];
      }
    }
    __syncthreads();
    if (colh == 0) {
#pragma unroll
      for (int m = 0; m < 4; ++m)
#pragma unroll
        for (int j = 0; j < 4; ++j)
          inv[m][j] = red[256 + rowh * 128 + m * 16 + fq * 4 + j];
    }
#pragma unroll
    for (int m = 0; m < 4; ++m)
#pragma unroll
      for (int n = 0; n < 8; ++n) {
        const int col = colh * 128 + n * 16 + fr;
#pragma unroll
        for (int j = 0; j < 4; ++j) {
          const int r = blk0 + rowh * 64 + m * 16 + fq * 4 + j;
          if (r < M) {
            float v = acc[m][n][j] * inv[m][j];
            Cf[(size_t)r * ldc + col] = v;
            if (Obf) Obf[(size_t)r * ldo + col] = f2b(v);
          }
        }
      }
  }
}

// ---------------- small GEMM (init only): C = A * Bt^T (+bias), f32 out ----------
__global__ __launch_bounds__(256)
void gemm_k(const short* __restrict__ A, int lda,
            const short* __restrict__ Bt, int ldb,
            int M, int K,
            float* __restrict__ Cf, int ldc,
            const float* __restrict__ bias)
{
  __shared__ short bt[256 * 72];
  const int tid = threadIdx.x;
  const int w = tid >> 6;
  const int lane = tid & 63;
  const int fr = lane & 15;
  const int fq = lane >> 4;
  const int col0 = blockIdx.y << 8;
  const int rowbase = blockIdx.x * 64 + w * 16;
  const int arow = min(rowbase + fr, M - 1);
  const long abase = (long)arow * lda + fq * 8;

  f32x4 acc[16];
#pragma unroll
  for (int i = 0; i < 16; ++i) { acc[i][0] = 0.f; acc[i][1] = 0.f; acc[i][2] = 0.f; acc[i][3] = 0.f; }

  for (int kc = 0; kc < K; kc += 64) {
    __syncthreads();
    {
      const short* g = Bt + (long)(col0 + tid) * ldb + kc;
      short* l = &bt[tid * 72];
#pragma unroll
      for (int i = 0; i < 8; ++i)
        *(short8*)(l + i * 8) = *(const short8*)(g + i * 8);
    }
    __syncthreads();
#pragma unroll
    for (int ks = 0; ks < 2; ++ks) {
      short8 a = *(const short8*)(A + abase + kc + ks * 32);
#pragma unroll
      for (int ct = 0; ct < 16; ++ct) {
        short8 b = *(const short8*)&bt[(ct * 16 + fr) * 72 + ks * 32 + fq * 8];
        acc[ct] = __builtin_amdgcn_mfma_f32_16x16x32_bf16(a, b, acc[ct], 0, 0, 0);
      }
    }
  }

  const int crow = rowbase + fq * 4;
#pragma unroll
  for (int ct = 0; ct < 16; ++ct) {
    const int gcol = col0 + ct * 16 + fr;
#pragma unroll
    for (int j = 0; j < 4; ++j) {
      const int r = crow + j;
      if (r < M) {
        float v = acc[ct][j];
        if (bias) v += bias[gcol];
        Cf[(long)r * ldc + gcol] = v;
      }
    }
  }
}

// ---------------- fused GRU GEMMs: z=0 -> gx, z=1 -> gh ---------------------------
__global__ __launch_bounds__(256)
void gru2_k(const short* __restrict__ x_inb, const short* __restrict__ h0b,
            const short* __restrict__ wihb, const short* __restrict__ whhb,
            const float* __restrict__ gxbase, const float* __restrict__ bhh,
            float* __restrict__ gx, float* __restrict__ gh)
{
  const short* A;  const short* Bt;  int ldb;
  float* Cf;  const float* Cadd;  const float* bias;
  if (blockIdx.z == 0) { A = x_inb; Bt = wihb + 256; ldb = 512; Cf = gx; Cadd = gxbase; bias = nullptr; }
  else                 { A = h0b;   Bt = whhb;       ldb = 256; Cf = gh; Cadd = nullptr; bias = bhh; }

  __shared__ short bt[256 * 72];
  const int tid = threadIdx.x;
  const int w = tid >> 6;
  const int lane = tid & 63;
  const int fr = lane & 15;
  const int fq = lane >> 4;
  const int col0 = blockIdx.y << 8;
  const int rowbase = blockIdx.x * 64 + w * 16;
  const int arow = min(rowbase + fr, R2 - 1);
  const long abase = (long)arow * 256 + fq * 8;

  f32x4 acc[16];
#pragma unroll
  for (int i = 0; i < 16; ++i) { acc[i][0] = 0.f; acc[i][1] = 0.f; acc[i][2] = 0.f; acc[i][3] = 0.f; }

  for (int kc = 0; kc < 256; kc += 64) {
    __syncthreads();
    {
      const short* g = Bt + (long)(col0 + tid) * ldb + kc;
      short* l = &bt[tid * 72];
#pragma unroll
      for (int i = 0; i < 8; ++i)
        *(short8*)(l + i * 8) = *(const short8*)(g + i * 8);
    }
    __syncthreads();
#pragma unroll
    for (int ks = 0; ks < 2; ++ks) {
      short8 a = *(const short8*)(A + abase + kc + ks * 32);
#pragma unroll
      for (int ct = 0; ct < 16; ++ct) {
        short8 b = *(const short8*)&bt[(ct * 16 + fr) * 72 + ks * 32 + fq * 8];
        acc[ct] = __builtin_amdgcn_mfma_f32_16x16x32_bf16(a, b, acc[ct], 0, 0, 0);
      }
    }
  }

  const int crow = rowbase + fq * 4;
#pragma unroll
  for (int ct = 0; ct < 16; ++ct) {
    const int gcol = col0 + ct * 16 + fr;
#pragma unroll
    for (int j = 0; j < 4; ++j) {
      const int r = crow + j;
      if (r < R2) {
        float v = acc[ct][j];
        if (Cadd) v += Cadd[(long)r * 768 + gcol];
        if (bias) v += bias[gcol];
        Cf[(long)r * 768 + gcol] = v;
      }
    }
  }
}

// ---------------- init: h = l2norm(dynamic_emb) -> bf16 into Acat halfB ----------
__global__ __launch_bounds__(256)
void l2init_k(const float* __restrict__ de, short* __restrict__ hb)
{
  const int w = threadIdx.x >> 6, lane = threadIdx.x & 63;
  const int row = blockIdx.x * 4 + w;
  f32x4 v = *(const f32x4*)&de[(long)row * H + lane * 4];
  float s = v[0]*v[0] + v[1]*v[1] + v[2]*v[2] + v[3]*v[3];
  s += __shfl_xor(s, 1, 64);  s += __shfl_xor(s, 2, 64);
  s += __shfl_xor(s, 4, 64);  s += __shfl_xor(s, 8, 64);
  s += __shfl_xor(s, 16, 64); s += __shfl_xor(s, 32, 64);
  float sc = 1.f / fmaxf(sqrtf(s), 1e-12f);
  short4v o;
  o[0] = f2b(v[0]*sc); o[1] = f2b(v[1]*sc); o[2] = f2b(v[2]*sc); o[3] = f2b(v[3]*sc);
  *(short4v*)&hb[(long)row * 512 + lane * 4] = o;
}

// ---------------- merged weight prep ---------------------------------------------
__global__ __launch_bounds__(256)
void prep_k(const float* __restrict__ wn, const float* __restrict__ lw,
            const float* __restrict__ ew, const float* __restrict__ wih,
            const float* __restrict__ whh, const float* __restrict__ erel,
            short* __restrict__ wcatb, short* __restrict__ evt,
            short* __restrict__ wihb, short* __restrict__ whhb,
            short* __restrict__ erelb, float* __restrict__ h0, short* __restrict__ h0b)
{
  long i = (long)blockIdx.x * 256 + threadIdx.x;
  if (i < (long)NL * 256 * 512) {
    int l = (int)(i / (256 * 512));
    int rem = (int)(i % (256 * 512));
    int j = rem / 512;
    int k = rem % 512;
    float v = (k < 256) ? wn[(long)l * 65536 + k * 256 + j]
                        : lw[(long)l * 65536 + (k - 256) * 256 + j];
    wcatb[i] = f2b(v);
    return;
  }
  i -= (long)NL * 256 * 512;
  if (i < (long)NL * 65536) {
    int l = (int)(i >> 16);
    int rem = (int)(i & 65535);
    int c = rem >> 8, k = rem & 255;
    evt[i] = f2b(ew[(long)l * 65536 + k * 256 + c]);
    return;
  }
  i -= (long)NL * 65536;
  if (i < 768 * 512) { wihb[i] = f2b(wih[i]); return; }
  i -= 768 * 512;
  if (i < 768 * 256) { whhb[i] = f2b(whh[i]); return; }
  i -= 768 * 256;
  if (i < (long)R2 * H) {
    float v = erel[i];
    erelb[i] = f2b(v); h0[i] = v; h0b[i] = f2b(v);
  }
}
#define PREP_N ((long)NL * 256 * 512 + (long)NL * 65536 + 768 * 512 + 768 * 256 + (long)R2 * H)

// ---------------- batched zero of all 4 steps' counters (padded) ------------------
__global__ __launch_bounds__(256)
void zero_all_k(unsigned* __restrict__ deg, unsigned* __restrict__ curd,
                unsigned* __restrict__ cnt, unsigned* __restrict__ cur,
                unsigned* __restrict__ nz, unsigned* __restrict__ flags)
{
  const int t = blockIdx.y;
  int i = blockIdx.x * 256 + threadIdx.x;
  if (i < N_ENTS) { deg[(long)t * N_ENTS + i] = 0u; curd[(long)t * N_ENTS + i] = 0u; }
  if (i < R2) { cnt[((long)t * R2 + i) * CPAD] = 0u; cur[((long)t * R2 + i) * CPAD] = 0u; }
  if (i < SCAN_NB) flags[t * SCAN_NB + i] = 0u;
  if (i == 0) nz[t * CPAD] = 0u;
}

// ---------------- batched counting: rel histogram (LDS) + dst degree --------------
__global__ __launch_bounds__(256)
void count_all_k(const int* __restrict__ relA, const int* __restrict__ dstA,
                 unsigned* __restrict__ cntA, unsigned* __restrict__ degA)
{
  const int t = blockIdx.y;
  const int* rel = relA + (long)t * NM;
  const int* dstv = dstA + (long)t * NE;
  unsigned* cnt = cntA + (long)t * R2 * CPAD;
  unsigned* deg = degA + (long)t * N_ENTS;
  __shared__ unsigned lh[R2];
  for (int i = threadIdx.x; i < R2; i += 256) lh[i] = 0;
  __syncthreads();
  for (long i = (long)blockIdx.x * 256 + threadIdx.x; i < NM; i += (long)gridDim.x * 256)
    atomicAdd(&lh[rel[i]], 1u);
  for (long i = (long)blockIdx.x * 256 + threadIdx.x; i < NE; i += (long)gridDim.x * 256)
    atomicAdd(&deg[dstv[i]], 1u);
  __syncthreads();
  for (int i = threadIdx.x; i < R2; i += 256)
    if (lh[i]) atomicAdd(&cnt[i * CPAD], lh[i]);
}

// ---------------- batched scans: decoupled lookback (deg) + rel prefix ------------
__global__ __launch_bounds__(256)
void scan_all_k(const unsigned* __restrict__ degA, unsigned* __restrict__ offdA,
                unsigned* __restrict__ flagsA,
                unsigned* __restrict__ zlA, unsigned* __restrict__ nzA,
                const unsigned* __restrict__ cntA, unsigned* __restrict__ offA)
{
  const int t = blockIdx.y;
  if (blockIdx.x == SCAN_NB) {           // rel-histogram prefix (512-slot HS)
    const unsigned* cnt = cntA + (long)t * R2 * CPAD;
    unsigned* off = offA + t * (R2 + 1);
    __shared__ unsigned sr[512];
    const int tt = threadIdx.x;
    sr[tt] = (tt < R2) ? cnt[tt * CPAD] : 0u;
    sr[tt + 256] = (tt + 256 < R2) ? cnt[(tt + 256) * CPAD] : 0u;
    __syncthreads();
#pragma unroll
    for (int d = 1; d < 512; d <<= 1) {
      unsigned v0 = (tt >= d) ? sr[tt - d] : 0u;
      unsigned v1 = (tt + 256 >= d) ? sr[tt + 256 - d] : 0u;
      __syncthreads();
      sr[tt] += v0; sr[tt + 256] += v1;
      __syncthreads();
    }
    if (tt < R2) off[tt] = (tt == 0) ? 0u : sr[tt - 1];
    if (tt + 256 < R2) off[tt + 256] = sr[tt + 255];
    if (tt == 0) off[R2] = sr[R2 - 1];
    return;
  }
  const unsigned* deg = degA + (long)t * N_ENTS;
  unsigned* offd = offdA + (long)t * (N_ENTS + 1);
  unsigned* flags = flagsA + t * SCAN_NB;
  unsigned* zl = zlA + (long)t * N_ENTS;
  unsigned* nz = nzA + t * CPAD;
  __shared__ unsigned s[256];
  __shared__ unsigned sexc;
  const int tid = threadIdx.x;
  const int b = blockIdx.x;
  const int i = b * 256 + tid;
  unsigned v = (i < N_ENTS) ? deg[i] : 0u;
  s[tid] = v;
  __syncthreads();
#pragma unroll
  for (int d = 1; d < 256; d <<= 1) {
    unsigned t2 = (tid >= d) ? s[tid - d] : 0u;
    __syncthreads();
    s[tid] += t2;
    __syncthreads();
  }
  const unsigned total = s[255];
  if (tid == 0) {
    if (b == 0) {
      __threadfence();
      atomicExch(&flags[0], (2u << 30) | total);
      sexc = 0u;
    } else {
      __threadfence();
      atomicExch(&flags[b], (1u << 30) | total);
      unsigned exc = 0u;
      int j = b - 1;
      while (j >= 0) {
        unsigned f;
        do { f = atomicAdd(&flags[j], 0u); } while ((f >> 30) == 0u);
        exc += f & 0x3FFFFFFFu;
        if ((f >> 30) == 2u) break;
        --j;
      }
      __threadfence();
      atomicExch(&flags[b], (2u << 30) | (exc + total));
      sexc = exc;
    }
  }
  __syncthreads();
  const unsigned exc = sexc;
  if (i < N_ENTS) {
    offd[i] = exc + s[tid] - v;
    if (v == 0u) { unsigned p2 = atomicAdd(nz, 1u); zl[p2] = i; }
  }
  if (i == 0) offd[N_ENTS] = NE;
}

// ---------------- batched scatter: rel-CSR (ent) + dst-CSR (src,etype int2) ------
__global__ __launch_bounds__(256)
void scatter_all_k(const int* __restrict__ relA, const int* __restrict__ entA,
                   const unsigned* __restrict__ offA, unsigned* __restrict__ curA,
                   int* __restrict__ seA,
                   const int* __restrict__ srcA, const int* __restrict__ dstA,
                   const int* __restrict__ etA, const unsigned* __restrict__ offdA,
                   unsigned* __restrict__ curdA, int2* __restrict__ se2A)
{
  const int t = blockIdx.y;
  if (blockIdx.x < 256) {
    const int* rel = relA + (long)t * NM;
    const int* ent = entA + (long)t * NM;
    const unsigned* off = offA + t * (R2 + 1);
    unsigned* cur = curA + (long)t * R2 * CPAD;
    int* se = seA + (long)t * NM;
    for (long i = (long)blockIdx.x * 256 + threadIdx.x; i < NM; i += 256l * 256) {
      int r = rel[i];
      unsigned p = atomicAdd(&cur[r * CPAD], 1u);
      se[off[r] + p] = ent[i];
    }
  } else {
    const int* srcv = srcA + (long)t * NE;
    const int* dstv = dstA + (long)t * NE;
    const int* etv = etA + (long)t * NE;
    const unsigned* offd = offdA + (long)t * (N_ENTS + 1);
    unsigned* curd = curdA + (long)t * N_ENTS;
    int2* se2 = se2A + (long)t * NE;
    for (long i = (long)(blockIdx.x - 256) * 256 + threadIdx.x; i < NE; i += 512l * 256) {
      int d = dstv[i];
      unsigned p = atomicAdd(&curd[d], 1u);
      se2[offd[d] + p] = make_int2(srcv[i], etv[i]);
    }
  }
}

// ---------------- segment-sum partials (x4 split), 16B/lane, 2 entries/wave -------
__global__ __launch_bounds__(256)
void segpart_k(const unsigned* __restrict__ off, const int* __restrict__ se,
               const short* __restrict__ hb, float* __restrict__ xinf)
{
  __shared__ float red[4][256];
  const int r = blockIdx.x >> 2, s = blockIdx.x & 3;
  const int w = threadIdx.x >> 6, lane = threadIdx.x & 63;
  const int half = lane >> 5, sl = lane & 31;
  const unsigned b = off[r], e = off[r + 1], len = e - b;
  const unsigned lo = b + ((len * s) >> 2), hi = b + ((len * (s + 1)) >> 2);
  float a[8];
#pragma unroll
  for (int j = 0; j < 8; ++j) a[j] = 0.f;
  unsigned i = lo + w * 2;
  for (; i + 10 <= hi; i += 16) {          // two pairs per wave per iter
    int e0 = se[i + half];
    int e1 = se[i + 8 + half];
    short8 h0v = *(const short8*)&hb[(long)e0 * 512 + sl * 8];
    short8 h1v = *(const short8*)&hb[(long)e1 * 512 + sl * 8];
#pragma unroll
    for (int j = 0; j < 8; ++j) a[j] += b2f(h0v[j]) + b2f(h1v[j]);
  }
  for (; i + 2 <= hi; i += 8) {
    int e0 = se[i + half];
    short8 hv = *(const short8*)&hb[(long)e0 * 512 + sl * 8];
#pragma unroll
    for (int j = 0; j < 8; ++j) a[j] += b2f(hv[j]);
  }
  if (i + half < hi) {
    int e0 = se[i + half];
    short8 hv = *(const short8*)&hb[(long)e0 * 512 + sl * 8];
#pragma unroll
    for (int j = 0; j < 8; ++j) a[j] += b2f(hv[j]);
  }
#pragma unroll
  for (int j = 0; j < 8; ++j) a[j] += __shfl_xor(a[j], 32, 64);
  if (half == 0) {
#pragma unroll
    for (int j = 0; j < 8; ++j) red[w][sl * 8 + j] = a[j];
  }
  __syncthreads();
  const int t = threadIdx.x;
  xinf[((long)s * R2 + r) * 256 + t] =
      (red[0][t] + red[1][t]) + (red[2][t] + red[3][t]);
}

__global__ __launch_bounds__(256)
void segfin_k(const float* __restrict__ xinf, const unsigned* __restrict__ cnt,
              short* __restrict__ x_inb)
{
  const int r = blockIdx.x, tid = threadIdx.x;
  float v = xinf[(long)r * 256 + tid] + xinf[((long)R2 + r) * 256 + tid]
          + xinf[((long)2 * R2 + r) * 256 + tid] + xinf[((long)3 * R2 + r) * 256 + tid];
  v /= fmaxf((float)cnt[r * CPAD], 1.f);
  x_inb[(long)r * 256 + tid] = f2b(v);
}

// ---------------- GRU gates ------------------------------------------------------
__global__ __launch_bounds__(256)
void gate_k(const float* __restrict__ gx, const float* __restrict__ gh,
            float* __restrict__ h0, short* __restrict__ h0b, float* __restrict__ relout)
{
  __shared__ float red[4];
  const int r = blockIdx.x, c = threadIdx.x;
  const long b = (long)r * 768;
  float xr = gx[b + c], xz = gx[b + 256 + c], xn = gx[b + 512 + c];
  float hr = gh[b + c], hz = gh[b + 256 + c], hn = gh[b + 512 + c];
  float rr = 1.f / (1.f + expf(-(xr + hr)));
  float z  = 1.f / (1.f + expf(-(xz + hz)));
  float nn = tanhf(xn + rr * hn);
  float v = (1.f - z) * nn + z * h0[(long)r * H + c];
  float s = v * v;
  s += __shfl_xor(s, 1, 64);  s += __shfl_xor(s, 2, 64);
  s += __shfl_xor(s, 4, 64);  s += __shfl_xor(s, 8, 64);
  s += __shfl_xor(s, 16, 64); s += __shfl_xor(s, 32, 64);
  const int w = c >> 6;
  if ((c & 63) == 0) red[w] = s;
  __syncthreads();
  float tot = (red[0] + red[1]) + (red[2] + red[3]);
  float sc = 1.f / fmaxf(sqrtf(tot), 1e-12f);
  v *= sc;
  h0[(long)r * H + c] = v;
  h0b[(long)r * H + c] = f2b(v);
  relout[(long)r * H + c] = v;
}

// ---------------- layer-0 aggregation: 16B/lane, 2 edges/wave, emits rsum --------
__global__ __launch_bounds__(256)
void agg_first_k(const int2* __restrict__ se2, const unsigned* __restrict__ offd,
                 const short* __restrict__ hb, const short* __restrict__ h0b,
                 short* __restrict__ rsum, short* __restrict__ acat)
{
  const int w = threadIdx.x >> 6, lane = threadIdx.x & 63;
  const int half = lane >> 5, sl = lane & 31;
  const int row = blockIdx.x * 4 + w;
  const unsigned b = offd[row], e = offd[row + 1];
  float ha[8], ra[8];
#pragma unroll
  for (int j = 0; j < 8; ++j) { ha[j] = 0.f; ra[j] = 0.f; }
  unsigned i = b;
  for (; i + 4 <= e; i += 4) {
    int2 e0 = se2[i + half];
    int2 e1 = se2[i + 2 + half];
    short8 h0v = *(const short8*)&hb[(long)e0.x * 512 + sl * 8];
    short8 r0v = *(const short8*)&h0b[(long)e0.y * 256 + sl * 8];
    short8 h1v = *(const short8*)&hb[(long)e1.x * 512 + sl * 8];
    short8 r1v = *(const short8*)&h0b[(long)e1.y * 256 + sl * 8];
#pragma unroll
    for (int j = 0; j < 8; ++j) {
      ha[j] += b2f(h0v[j]) + b2f(h1v[j]);
      ra[j] += b2f(r0v[j]) + b2f(r1v[j]);
    }
  }
  for (; i < e; i += 2) {
    if (i + half < e) {
      int2 e0 = se2[i + half];
      short8 hv = *(const short8*)&hb[(long)e0.x * 512 + sl * 8];
      short8 rv = *(const short8*)&h0b[(long)e0.y * 256 + sl * 8];
#pragma unroll
      for (int j = 0; j < 8; ++j) { ha[j] += b2f(hv[j]); ra[j] += b2f(rv[j]); }
    }
  }
#pragma unroll
  for (int j = 0; j < 8; ++j) {
    ha[j] += __shfl_xor(ha[j], 32, 64);
    ra[j] += __shfl_xor(ra[j], 32, 64);
  }
  if (half == 0) {
    const float nm = 1.f / fmaxf((float)(e - b), 1.f);
    short8 rs, o;
#pragma unroll
    for (int j = 0; j < 8; ++j) {
      rs[j] = f2b(ra[j]);
      o[j] = f2b((ha[j] + ra[j]) * nm);
    }
    *(short8*)&rsum[(long)row * 256 + sl * 8] = rs;
    *(short8*)&acat[(long)row * 512 + sl * 8] = o;
  }
}

// ---------------- layer-1 aggregation: reuses rsum, 16B/lane, 2 edges/wave -------
__global__ __launch_bounds__(256)
void agg_second_k(const int2* __restrict__ se2, const unsigned* __restrict__ offd,
                  const short* __restrict__ hb, const short* __restrict__ rsum,
                  short* __restrict__ acat)
{
  const int w = threadIdx.x >> 6, lane = threadIdx.x & 63;
  const int half = lane >> 5, sl = lane & 31;
  const int row = blockIdx.x * 4 + w;
  const unsigned b = offd[row], e = offd[row + 1];
  float ha[8];
#pragma unroll
  for (int j = 0; j < 8; ++j) ha[j] = 0.f;
  unsigned i = b;
  for (; i + 4 <= e; i += 4) {
    int2 e0 = se2[i + half];
    int2 e1 = se2[i + 2 + half];
    short8 h0v = *(const short8*)&hb[(long)e0.x * 512 + sl * 8];
    short8 h1v = *(const short8*)&hb[(long)e1.x * 512 + sl * 8];
#pragma unroll
    for (int j = 0; j < 8; ++j) ha[j] += b2f(h0v[j]) + b2f(h1v[j]);
  }
  for (; i < e; i += 2) {
    if (i + half < e) {
      int2 e0 = se2[i + half];
      short8 hv = *(const short8*)&hb[(long)e0.x * 512 + sl * 8];
#pragma unroll
      for (int j = 0; j < 8; ++j) ha[j] += b2f(hv[j]);
    }
  }
#pragma unroll
  for (int j = 0; j < 8; ++j) ha[j] += __shfl_xor(ha[j], 32, 64);
  if (half == 0) {
    short8 rs = *(const short8*)&rsum[(long)row * 256 + sl * 8];
    const float nm = 1.f / fmaxf((float)(e - b), 1.f);
    short8 o;
#pragma unroll
    for (int j = 0; j < 8; ++j) o[j] = f2b((ha[j] + b2f(rs[j])) * nm);
    *(short8*)&acat[(long)row * 512 + sl * 8] = o;
  }
}

// ---------------- deg==0 fixup: row = rrelu(hc @ evolve_w) (+l2norm if final) ----
template<int FINAL>
__global__ __launch_bounds__(256)
void fixup_k(const unsigned* __restrict__ nz, const unsigned* __restrict__ zl,
             const short* __restrict__ hbc, const short* __restrict__ evt,
             short* __restrict__ hbn, float* __restrict__ outF)
{
  __shared__ float x[H];
  __shared__ float red[4];
  const unsigned n = *nz;
  const short* wrow = evt + (long)threadIdx.x * 256;
  for (unsigned zi = blockIdx.x; zi < n; zi += gridDim.x) {
    const int row = zl[zi];
    __syncthreads();
    x[threadIdx.x] = b2f(hbc[(long)row * 512 + threadIdx.x]);
    __syncthreads();
    float acc = 0.f;
#pragma unroll
    for (int k0 = 0; k0 < H; k0 += 8) {
      short8 wv = *(const short8*)&wrow[k0];
      acc += x[k0]     * b2f(wv[0]) + x[k0 + 1] * b2f(wv[1])
           + x[k0 + 2] * b2f(wv[2]) + x[k0 + 3] * b2f(wv[3])
           + x[k0 + 4] * b2f(wv[4]) + x[k0 + 5] * b2f(wv[5])
           + x[k0 + 6] * b2f(wv[6]) + x[k0 + 7] * b2f(wv[7]);
    }
    float v = acc >= 0.f ? acc : acc * SLOPE;
    if (FINAL) {
      float s = v * v;
      s += __shfl_xor(s, 1, 64);  s += __shfl_xor(s, 2, 64);
      s += __shfl_xor(s, 4, 64);  s += __shfl_xor(s, 8, 64);
      s += __shfl_xor(s, 16, 64); s += __shfl_xor(s, 32, 64);
      const int w = threadIdx.x >> 6;
      if ((threadIdx.x & 63) == 0) red[w] = s;
      __syncthreads();
      float tot = (red[0] + red[1]) + (red[2] + red[3]);
      float sc = 1.f / fmaxf(sqrtf(tot), 1e-12f);
      v *= sc;
      outF[(long)row * H + threadIdx.x] = v;
    }
    if (hbn) hbn[(long)row * 512 + threadIdx.x] = f2b(v);
  }
}

// =================================================================================
extern "C" void kernel_launch(void* const* d_in, const int* in_sizes, int n_in,
                              void* d_out, int out_size, void* d_ws, size_t ws_size,
                              hipStream_t stream)
{
  (void)in_sizes; (void)n_in; (void)out_size; (void)ws_size;
  const int* src = (const int*)d_in[0];
  const int* dst = (const int*)d_in[1];
  const int* ety = (const int*)d_in[2];
  const int* r2e_ent = (const int*)d_in[3];
  const int* r2e_rel = (const int*)d_in[4];
  const float* dyn = (const float*)d_in[5];
  const float* erel = (const float*)d_in[6];
  const float* wn = (const float*)d_in[7];
  const float* lw = (const float*)d_in[8];
  const float* ew = (const float*)d_in[9];
  const float* wih = (const float*)d_in[10];
  const float* whh = (const float*)d_in[11];
  const float* bih = (const float*)d_in[12];
  const float* bhh = (const float*)d_in[13];

  float* out = (float*)d_out;
  float* hist = out;
  float* rels = out + (long)TSTEPS * N_ENTS * H;

  char* p = (char*)d_ws;
  auto alloc = [&](size_t n) { char* r = p; p += (n + 255) & ~(size_t)255; return r; };
  short*    AcatA  = (short*)alloc((size_t)N_ENTS * 512 * 2);
  short*    AcatB  = (short*)alloc((size_t)N_ENTS * 512 * 2);
  short*    rsum   = (short*)alloc((size_t)N_ENTS * 256 * 2);
  unsigned* deg    = (unsigned*)alloc((size_t)TSTEPS * N_ENTS * 4);
  unsigned* offd   = (unsigned*)alloc((size_t)TSTEPS * (N_ENTS + 1) * 4);
  unsigned* curd   = (unsigned*)alloc((size_t)TSTEPS * N_ENTS * 4);
  unsigned* flags  = (unsigned*)alloc((size_t)TSTEPS * SCAN_NB * 4);
  int2*     se2    = (int2*)alloc((size_t)TSTEPS * NE * 8);
  unsigned* zl     = (unsigned*)alloc((size_t)TSTEPS * N_ENTS * 4);
  unsigned* nz     = (unsigned*)alloc((size_t)TSTEPS * CPAD * 4);
  unsigned* cnt    = (unsigned*)alloc((size_t)TSTEPS * R2 * CPAD * 4);
  unsigned* off    = (unsigned*)alloc((size_t)TSTEPS * (R2 + 1) * 4);
  unsigned* cur    = (unsigned*)alloc((size_t)TSTEPS * R2 * CPAD * 4);
  int*      se     = (int*)alloc((size_t)TSTEPS * NM * 4);
  float*    xinf   = (float*)alloc((size_t)4 * R2 * 256 * 4);
  short*    x_inb  = (short*)alloc((size_t)R2 * H * 2);
  float*    gxbase = (float*)alloc((size_t)R2 * 768 * 4);
  float*    gx     = (float*)alloc((size_t)R2 * 768 * 4);
  float*    gh     = (float*)alloc((size_t)R2 * 768 * 4);
  float*    h0     = (float*)alloc((size_t)R2 * H * 4);
  short*    h0b    = (short*)alloc((size_t)R2 * H * 2);
  short*    erelb  = (short*)alloc((size_t)R2 * H * 2);
  short*    wcatb  = (short*)alloc((size_t)NL * 256 * 512 * 2);
  short*    evt    = (short*)alloc((size_t)NL * H * H * 2);
  short*    wihb   = (short*)alloc((size_t)768 * 512 * 2);
  short*    whhb   = (short*)alloc((size_t)768 * 256 * 2);

  prep_k<<<(int)((PREP_N + 255) / 256), 256, 0, stream>>>(
      wn, lw, ew, wih, whh, erel, wcatb, evt, wihb, whhb, erelb, h0, h0b);
  l2init_k<<<N_ENTS / 4, 256, 0, stream>>>(dyn, AcatA + 256);

  // gx_base = emb_rel @ W_ih[:, :256]^T + b_ih   (step-invariant)
  gemm_k<<<dim3(8, 3), 256, 0, stream>>>(erelb, 256, wihb, 512, R2, 256,
                                         gxbase, 768, bih);

  // ---- batched CSR build for ALL steps (depends only on int inputs) -------------
  zero_all_k<<<dim3(SCAN_NB, TSTEPS), 256, 0, stream>>>(deg, curd, cnt, cur, nz, flags);
  count_all_k<<<dim3(512, TSTEPS), 256, 0, stream>>>(r2e_rel, dst, cnt, deg);
  scan_all_k<<<dim3(SCAN_NB + 1, TSTEPS), 256, 0, stream>>>(deg, offd, flags, zl, nz, cnt, off);
  scatter_all_k<<<dim3(768, TSTEPS), 256, 0, stream>>>(r2e_rel, r2e_ent, off, cur, se,
                                                       src, dst, ety, offd, curd, se2);

  short* Acur = AcatA;
  short* Anxt = AcatB;

  for (int t = 0; t < TSTEPS; ++t) {
    float* hist_t = hist + (long)t * N_ENTS * H;
    float* rels_t = rels + (long)t * R2 * H;
    const unsigned* off_t  = off + t * (R2 + 1);
    const int*      se_t   = se + (long)t * NM;
    const unsigned* offd_t = offd + (long)t * (N_ENTS + 1);
    const int2*     se2_t  = se2 + (long)t * NE;
    const unsigned* cnt_t  = cnt + (long)t * R2 * CPAD;
    const unsigned* nz_t   = nz + t * CPAD;
    const unsigned* zl_t   = zl + (long)t * N_ENTS;

    // relation mean (split x4) + GRU
    segpart_k<<<R2 * 4, 256, 0, stream>>>(off_t, se_t, Acur + 256, xinf);
    segfin_k<<<R2, 256, 0, stream>>>(xinf, cnt_t, x_inb);
    gru2_k<<<dim3(8, 3, 2), 256, 0, stream>>>(x_inb, h0b, wihb, whhb, gxbase, bhh, gx, gh);
    gate_k<<<R2, 256, 0, stream>>>(gx, gh, h0, h0b, rels_t);

    // layer 0
    agg_first_k<<<N_ENTS / 4, 256, 0, stream>>>(se2_t, offd_t, Acur + 256, h0b, rsum, Acur);
    gemm_big<1><<<391, 256, 0, stream>>>(Acur, 512, wcatb, 512,
                                         N_ENTS, 512, nullptr, 0, Anxt + 256, 512);
    fixup_k<0><<<512, 256, 0, stream>>>(nz_t, zl_t, Acur + 256, evt, Anxt + 256, nullptr);
    { short* tmp = Acur; Acur = Anxt; Anxt = tmp; }

    // layer 1
    agg_second_k<<<N_ENTS / 4, 256, 0, stream>>>(se2_t, offd_t, Acur + 256, rsum, Acur);
    const bool last = (t == TSTEPS - 1);
    gemm_big<2><<<391, 256, 0, stream>>>(Acur, 512, wcatb + 256 * 512, 512,
                                         N_ENTS, 512, hist_t, 256,
                                         last ? nullptr : (Anxt + 256), 512);
    fixup_k<1><<<512, 256, 0, stream>>>(nz_t, zl_t, Acur + 256, evt + (long)H * H,
                                        last ? nullptr : (Anxt + 256), hist_t);
    { short* tmp = Acur; Acur = Anxt; Anxt = tmp; }
  }
}